// Round 1
// baseline (1242.124 us; speedup 1.0000x reference)
//
#include <hip/hip_runtime.h>
#include <cstdint>
#include <cmath>

// ---------------------------------------------------------------------------
// HawkBlock on MI355X (gfx950). Round 5.
// R4 post-mortem: gemm1 at 916 TF = the m97-structure ceiling (MfmaUtil 41%,
// HBM 27%, bank-conflict 0 -> schedule-bound). R5: port all big GEMMs to the
// 256^2 / BK=64 / 8-wave phase-split schedule with counted vmcnt (T3+T4+T5
// on top of the existing T2 swizzle). 512 threads, 128KB double-buffered LDS,
// 4 phases per K-tile, vmcnt(4) once per K-tile (never 0 in steady state).
// Dual-B variant keeps the xin/gate and silu*up fusions (256x128 per matrix).
// Scan / rmsnorm / f2b unchanged from R4.
// ---------------------------------------------------------------------------

typedef unsigned short u16;
typedef _Float16 f16;
typedef __bf16 bf16x8 __attribute__((ext_vector_type(8)));
typedef float  f32x4  __attribute__((ext_vector_type(4)));

#define HID   1024
#define DREC  2048
#define INTER 4096
#define BT    16384   // B*T rows
#define TLEN  4096
#define NCHAN 8192    // B * DREC
#define CHUNK 64
#define NCH   64      // TLEN / CHUNK
#define NPAIR 4096    // NCHAN/2 channel pairs

__device__ __forceinline__ float b2f(u16 u) {
  union { unsigned int i; float f; } v; v.i = ((unsigned int)u) << 16; return v.f;
}
__device__ __forceinline__ u16 f2bf(float f) {  // RNE
  unsigned int u = __builtin_bit_cast(unsigned int, f);
  u += 0x7FFFu + ((u >> 16) & 1u);
  return (u16)(u >> 16);
}
__device__ __forceinline__ float sigm(float x) { return 1.f / (1.f + expf(-x)); }

typedef __attribute__((address_space(1))) void as1_void;
typedef __attribute__((address_space(3))) void as3_void;
__device__ __forceinline__ void async16(const void* g, void* l) {
  __builtin_amdgcn_global_load_lds((as1_void*)g, (as3_void*)l, 16, 0, 0);
}

// Phase-discipline macros.
// BARSYNC: raw barrier + sched fence so stages can't hoist into the previous
//          phase's read-drain window.
// LGKM0:   drain own ds_reads; sched_barrier(0) required (guide rule #18 --
//          hipcc hoists register-only MFMA past inline-asm lgkmcnt).
// VMC(N):  counted vmem wait (T4). Memory clobber pins cross-phase order.
#define BARSYNC() do { __builtin_amdgcn_s_barrier(); __builtin_amdgcn_sched_barrier(0); } while (0)
#define LGKM0()   do { asm volatile("s_waitcnt lgkmcnt(0)" ::: "memory"); __builtin_amdgcn_sched_barrier(0); } while (0)
#define VMC(N)    do { asm volatile("s_waitcnt vmcnt(" #N ")" ::: "memory"); __builtin_amdgcn_sched_barrier(0); } while (0)
#define FENCE()   do { asm volatile("" ::: "memory"); __builtin_amdgcn_sched_barrier(0); } while (0)

// ---------------------------------------------------------------------------
// All 7 weight conversions in ONE kernel (unchanged).
__global__ void f2b_all(const float* s0, const float* s1, const float* s2,
                        const float* s3, const float* s4, const float* s5,
                        const float* s6,
                        u16* d0, u16* d1, u16* d2, u16* d3, u16* d4, u16* d5,
                        u16* d6) {
  int blk = blockIdx.x;
  const float* src; u16* dst; int rel;
  if      (blk < 2048)  { src = s0; dst = d0; rel = blk; }
  else if (blk < 4096)  { src = s1; dst = d1; rel = blk - 2048; }
  else if (blk < 8192)  { src = s2; dst = d2; rel = blk - 4096; }
  else if (blk < 10240) { src = s3; dst = d3; rel = blk - 8192; }
  else if (blk < 14336) { src = s4; dst = d4; rel = blk - 10240; }
  else if (blk < 18432) { src = s5; dst = d5; rel = blk - 14336; }
  else                  { src = s6; dst = d6; rel = blk - 18432; }
  int i = rel * 256 + threadIdx.x;
  float4 v = ((const float4*)src)[i];
  ushort4 o;
  o.x = f2bf(v.x); o.y = f2bf(v.y); o.z = f2bf(v.z); o.w = f2bf(v.w);
  ((ushort4*)dst)[i] = o;
}

// rmsnorm over rows of 1024 fp32, bf16 out (unchanged).
__global__ void rmsnorm_kernel(const float* __restrict__ x, const float* __restrict__ w,
                               u16* __restrict__ out) {
  const int row = blockIdx.x;
  const int tid = threadIdx.x;
  float4 v = ((const float4*)(x + (size_t)row * HID))[tid];
  float ss = v.x * v.x + v.y * v.y + v.z * v.z + v.w * v.w;
#pragma unroll
  for (int o = 32; o > 0; o >>= 1) ss += __shfl_down(ss, o);
  __shared__ float red[4];
  const int lane = tid & 63, wv = tid >> 6;
  if (lane == 0) red[wv] = ss;
  __syncthreads();
  float tot = red[0] + red[1] + red[2] + red[3];
  float sc = rsqrtf(tot * (1.f / (float)HID) + 1e-6f);
  float4 wv4 = ((const float4*)w)[tid];
  ushort4 o;
  o.x = f2bf(v.x * sc * wv4.x); o.y = f2bf(v.y * sc * wv4.y);
  o.z = f2bf(v.z * sc * wv4.z); o.w = f2bf(v.w * sc * wv4.w);
  ((ushort4*)(out + (size_t)row * HID))[tid] = o;
}

// ---------------------------------------------------------------------------
// 256-tile GEMM building blocks.
//
// Half-tile = 128 rows x 64 cols bf16 = 16KB; staged by 512 threads x 2 x
// global_load_lds_dwordx4 (2 vmcnt units per wave per half-tile). Chunk-XOR
// swizzle (measured conflict-free in R4: SQ_LDS_BANK_CONFLICT = 0) applied on
// the pre-swizzled GLOBAL source; LDS dest stays linear as global_load_lds
// requires (guide m104/m173).
__device__ __forceinline__ void stageG(const u16* __restrict__ g, int ldg,
                                       int rb, int k0, u16* lbase, int tid) {
#pragma unroll
  for (int i = 0; i < 2; ++i) {
    int p = i * 512 + tid;          // 16B-chunk index in [0,1024)
    int r = p >> 3;                 // local row 0..127
    int sg = (p & 7) ^ (r & 7);     // swizzled source chunk
    async16(g + (size_t)(rb + r) * ldg + (k0 + sg * 8), (char*)lbase + p * 16);
  }
}

// 4 M-fragments (rows rbase+{0,16,32,48}), both k-subtiles: 8 x ds_read_b128.
__device__ __forceinline__ void readA4(bf16x8 (&af)[4][2], const u16* base,
                                       int rbase, int quad) {
#pragma unroll
  for (int i = 0; i < 4; ++i) {
    int r = rbase + i * 16;
#pragma unroll
    for (int ks = 0; ks < 2; ++ks)
      af[i][ks] = ((const bf16x8*)base)[r * 8 + ((ks * 4 + quad) ^ (r & 7))];
  }
}
// 2 N-fragments, both k-subtiles: 4 x ds_read_b128.
__device__ __forceinline__ void readB2(bf16x8 (&bf)[2][2], const u16* base,
                                       int rbase, int quad) {
#pragma unroll
  for (int i = 0; i < 2; ++i) {
    int r = rbase + i * 16;
#pragma unroll
    for (int ks = 0; ks < 2; ++ks)
      bf[i][ks] = ((const bf16x8*)base)[r * 8 + ((ks * 4 + quad) ^ (r & 7))];
  }
}

// One C-quadrant: 16 MFMA under setprio(1) (T5; pays on phase-split only).
// All indices compile-time after unroll (rule #20).
template <int MI0, int NI0, int NA>
__device__ __forceinline__ void mfmaQ(f32x4 (&acc)[8][NA],
                                      const bf16x8 (&af)[4][2],
                                      const bf16x8 (&bf)[2][2]) {
  __builtin_amdgcn_s_setprio(1);
#pragma unroll
  for (int mi = 0; mi < 4; ++mi)
#pragma unroll
    for (int ni = 0; ni < 2; ++ni)
#pragma unroll
      for (int ks = 0; ks < 2; ++ks)
        acc[MI0 + mi][NI0 + ni] = __builtin_amdgcn_mfma_f32_16x16x32_bf16(
            af[mi][ks], bf[ni][ks], acc[MI0 + mi][NI0 + ni], 0, 0, 0);
  __builtin_amdgcn_s_setprio(0);
}

// ---------------------------------------------------------------------------
// Single-B 256x256 GEMM: C[M,N] = A[M,K] @ W[N,K]^T, 8 waves (2Mx4N), each
// wave owns 128x64. Phases per K-tile t (buf c=t&1):
//   ph1: read af(rows wm*128+0..63) + bfL(cols wn*64+0..31); issue A1,B1(t+1)
//   ph2: read bfH(cols +32..63)
//   ph3: read af(rows +64..127);                             issue B0(t+2)
//   ph4: (no reads)                                          issue A0(t+2)
//   each phase: BAR; lgkmcnt(0); 16 MFMA; BAR.  vmcnt(4) before ph4's BAR.
// Region hazards: A-halves of buf c last read ph3, B-halves ph2; all re-stage
// slots sit >=1 barrier after the drained reads. vmcnt(4) = the 2 youngest
// half-tiles (B0,A0 of t+2) may stay in flight; everything of t+1 complete.
enum { EPI_LOGIT = 0, EPI_ADDF = 1 };

template <int EPI>
__global__ __launch_bounds__(512, 2)
void gemm256(const u16* __restrict__ A, const u16* __restrict__ W,
             int K, int N, int ldA, int ldW,
             float* outf, f16* outz, const float* auxf) {
  __shared__ u16 sA[2][16384];   // [buf][256 rows x 64 cols]
  __shared__ u16 sB[2][16384];
  const int tid  = threadIdx.x;
  const int lane = tid & 63, wv = tid >> 6;
  const int wm   = wv >> 2, wn = wv & 3;
  const int lm   = lane & 15, quad = lane >> 4;
  const int row0 = blockIdx.x * 256, col0 = blockIdx.y * 256;
  const int NT   = K >> 6;

  f32x4 acc[8][4];
#pragma unroll
  for (int i = 0; i < 8; ++i)
#pragma unroll
    for (int j = 0; j < 4; ++j) acc[i][j] = (f32x4)0.f;

  // Prologue: tile0 fully + first 2 half-tiles of tile1 (issue order matters
  // for the vmcnt arithmetic -> FENCE between the age classes).
  stageG(A, ldA, row0,       0, sA[0],        tid);   // A0(0)
  stageG(W, ldW, col0,       0, sB[0],        tid);   // B0(0)
  stageG(A, ldA, row0 + 128, 0, sA[0] + 8192, tid);   // A1(0)
  stageG(W, ldW, col0 + 128, 0, sB[0] + 8192, tid);   // B1(0)
  FENCE();
  if (NT > 1) {
    stageG(W, ldW, col0, 64, sB[1], tid);             // B0(1)
    stageG(A, ldA, row0, 64, sA[1], tid);             // A0(1)
    VMC(4);                                           // tile0 landed
  } else {
    VMC(0);
  }
  BARSYNC();

  for (int t = 0; t < NT; ++t) {
    const int b = t & 1;
    const u16* Ab = sA[b];
    const u16* Bb = sB[b];
    bf16x8 af[4][2], bfL[2][2], bfH[2][2];

    // ---- phase 1 ----
    readA4(af, Ab, wm * 128 + lm, quad);
    readB2(bfL, Bb, wn * 64 + lm, quad);
    if (t + 1 < NT) {
      stageG(A, ldA, row0 + 128, (t + 1) * 64, sA[b ^ 1] + 8192, tid);  // A1(t+1)
      stageG(W, ldW, col0 + 128, (t + 1) * 64, sB[b ^ 1] + 8192, tid);  // B1(t+1)
    }
    BARSYNC(); LGKM0();
    mfmaQ<0, 0>(acc, af, bfL);
    BARSYNC();

    // ---- phase 2 ----
    readB2(bfH, Bb, wn * 64 + 32 + lm, quad);
    BARSYNC(); LGKM0();
    mfmaQ<0, 2>(acc, af, bfH);
    BARSYNC();

    // ---- phase 3 ----
    readA4(af, Ab, wm * 128 + 64 + lm, quad);
    if (t + 2 < NT) stageG(W, ldW, col0, (t + 2) * 64, sB[b], tid);     // B0(t+2)
    BARSYNC(); LGKM0();
    mfmaQ<4, 2>(acc, af, bfH);
    BARSYNC();

    // ---- phase 4 ----
    if (t + 2 < NT) stageG(A, ldA, row0, (t + 2) * 64, sA[b], tid);     // A0(t+2)
    mfmaQ<4, 0>(acc, af, bfL);
    if (t + 2 < NT) { VMC(4); } else { VMC(0); }
    BARSYNC();
  }

  // Epilogue. C/D layout: col = lane&15, row = quad*4 + reg (m89/m91).
#pragma unroll
  for (int mi = 0; mi < 8; ++mi) {
    const int rb = row0 + wm * 128 + mi * 16 + quad * 4;
#pragma unroll
    for (int ni = 0; ni < 4; ++ni) {
      const int cg = col0 + wn * 64 + ni * 16 + lm;
      f32x4 v = acc[mi][ni];
#pragma unroll
      for (int rr = 0; rr < 4; ++rr) {
        size_t idx = (size_t)(rb + rr) * N + cg;
        if constexpr (EPI == EPI_LOGIT) {
          outz[idx] = (f16)(v[rr] + auxf[cg]);   // pre-sigmoid logit, fp16
        } else {
          outf[idx] = v[rr] + auxf[idx];         // residual add; auxf may == outf
        }
      }
    }
  }
}

// ---------------------------------------------------------------------------
// Dual-B 256x128 GEMM (same schedule; B0 = matrix0's 128x64, B1 = matrix1's).
// Keeps the xin/gate and silu*up fusions without extra global round-trips.
// Phase MFMA mapping: ph1 acc0[0..3], ph2 acc1[0..3], ph3 acc1[4..7],
// ph4 acc0[4..7] (bf0 held live across ph2/ph3).
enum { EPI2_XG = 0, EPI2_SM = 1 };

template <int EPI>
__global__ __launch_bounds__(512, 2)
void gemm256d(const u16* __restrict__ A, const u16* __restrict__ W0,
              const u16* __restrict__ W1,
              int K, int N, int ldA, int ldW,
              u16* out0, u16* out1) {
  __shared__ u16 sA[2][16384];   // [buf][256 x 64]
  __shared__ u16 sB[2][16384];   // [buf][matrix0 128x64 | matrix1 128x64]
  const int tid  = threadIdx.x;
  const int lane = tid & 63, wv = tid >> 6;
  const int wm   = wv >> 2, wn = wv & 3;
  const int lm   = lane & 15, quad = lane >> 4;
  const int row0 = blockIdx.x * 256, col0 = blockIdx.y * 128;
  const int NT   = K >> 6;

  f32x4 acc0[8][2], acc1[8][2];
#pragma unroll
  for (int i = 0; i < 8; ++i)
#pragma unroll
    for (int j = 0; j < 2; ++j) { acc0[i][j] = (f32x4)0.f; acc1[i][j] = (f32x4)0.f; }

  stageG(A,  ldA, row0,       0, sA[0],        tid);   // A0(0)
  stageG(W0, ldW, col0,       0, sB[0],        tid);   // B0(0) = matrix0
  stageG(A,  ldA, row0 + 128, 0, sA[0] + 8192, tid);   // A1(0)
  stageG(W1, ldW, col0,       0, sB[0] + 8192, tid);   // B1(0) = matrix1
  FENCE();
  if (NT > 1) {
    stageG(W0, ldW, col0, 64, sB[1], tid);             // B0(1)
    stageG(A,  ldA, row0, 64, sA[1], tid);             // A0(1)
    VMC(4);
  } else {
    VMC(0);
  }
  BARSYNC();

  for (int t = 0; t < NT; ++t) {
    const int b = t & 1;
    const u16* Ab = sA[b];
    const u16* Bb = sB[b];
    bf16x8 af[4][2], bf0[2][2], bf1[2][2];

    // ---- phase 1 ----
    readA4(af, Ab, wm * 128 + lm, quad);
    readB2(bf0, Bb, wn * 32 + lm, quad);
    if (t + 1 < NT) {
      stageG(A,  ldA, row0 + 128, (t + 1) * 64, sA[b ^ 1] + 8192, tid);  // A1(t+1)
      stageG(W1, ldW, col0,       (t + 1) * 64, sB[b ^ 1] + 8192, tid);  // B1(t+1)
    }
    BARSYNC(); LGKM0();
    mfmaQ<0, 0>(acc0, af, bf0);
    BARSYNC();

    // ---- phase 2 ----
    readB2(bf1, Bb + 8192, wn * 32 + lm, quad);
    BARSYNC(); LGKM0();
    mfmaQ<0, 0>(acc1, af, bf1);
    BARSYNC();

    // ---- phase 3 ----
    readA4(af, Ab, wm * 128 + 64 + lm, quad);
    if (t + 2 < NT) stageG(W0, ldW, col0, (t + 2) * 64, sB[b], tid);     // B0(t+2)
    BARSYNC(); LGKM0();
    mfmaQ<4, 0>(acc1, af, bf1);
    BARSYNC();

    // ---- phase 4 ----
    if (t + 2 < NT) stageG(A, ldA, row0, (t + 2) * 64, sA[b], tid);      // A0(t+2)
    mfmaQ<4, 0>(acc0, af, bf0);
    if (t + 2 < NT) { VMC(4); } else { VMC(0); }
    BARSYNC();
  }

#pragma unroll
  for (int mi = 0; mi < 8; ++mi) {
    const int rb = row0 + wm * 128 + mi * 16 + quad * 4;
#pragma unroll
    for (int ni = 0; ni < 2; ++ni) {
      const int cg = col0 + wn * 32 + ni * 16 + lm;
#pragma unroll
      for (int rr = 0; rr < 4; ++rr) {
        size_t idx = (size_t)(rb + rr) * N + cg;
        float v0 = acc0[mi][ni][rr];
        float v1 = acc1[mi][ni][rr];
        if constexpr (EPI == EPI2_XG) {
          out0[idx] = f2bf(v0);                 // xin raw
          out1[idx] = f2bf(sigm(v1));           // gate
        } else {
          out0[idx] = f2bf(v0 * sigm(v0) * v1); // m = silu(g) * u
        }
      }
    }
  }
}

// ---------------------------------------------------------------------------
// Chunked scan (unchanged from R4).
__global__ void scan_phase1(const f16* __restrict__ z, const u16* __restrict__ xin,
                            float2* __restrict__ ch_h, float2* __restrict__ ch_p) {
  int gtid = blockIdx.x * 256 + threadIdx.x;
  int c = gtid >> 12;
  int pair = gtid & (NPAIR - 1);
  int b = pair >> 10;
  int d = (pair & 1023) * 2;
  size_t base = ((size_t)b * TLEN + (size_t)c * CHUNK) * DREC + d;
  float2 h = {0.f, 0.f}, P = {1.f, 1.f};
#pragma unroll 8
  for (int t = 0; t < CHUNK; ++t) {
    size_t i = base + (size_t)t * DREC;
    f16 z2[2]; *(uint32_t*)z2 = *(const uint32_t*)(z + i);
    u16 x2[2]; *(uint32_t*)x2 = *(const uint32_t*)(xin + i);
    float a0 = sigm((float)z2[0]), a1 = sigm((float)z2[1]);
    h.x = a0 * h.x + sqrtf(1.f - a0 * a0 + 1e-8f) * b2f(x2[0]);
    h.y = a1 * h.y + sqrtf(1.f - a1 * a1 + 1e-8f) * b2f(x2[1]);
    P.x *= a0; P.y *= a1;
  }
  ch_h[gtid] = h;
  ch_p[gtid] = P;
}

__global__ void scan_phase2(float2* __restrict__ ch_h, const float2* __restrict__ ch_p) {
  int pair = blockIdx.x * 256 + threadIdx.x;
  float2 H = {0.f, 0.f};
#pragma unroll
  for (int c = 0; c < NCH; ++c) {
    int i = c * NPAIR + pair;
    float2 he = ch_h[i];
    float2 P  = ch_p[i];
    ch_h[i] = H;
    H.x = he.x + P.x * H.x;
    H.y = he.y + P.y * H.y;
  }
}

__global__ void scan_phase3(const f16* __restrict__ z, const u16* __restrict__ xin,
                            u16* gate_y, const float2* __restrict__ ch_h) {
  int gtid = blockIdx.x * 256 + threadIdx.x;
  int c = gtid >> 12;
  int pair = gtid & (NPAIR - 1);
  int b = pair >> 10;
  int d = (pair & 1023) * 2;
  size_t base = ((size_t)b * TLEN + (size_t)c * CHUNK) * DREC + d;
  float2 h = ch_h[gtid];
#pragma unroll 8
  for (int t = 0; t < CHUNK; ++t) {
    size_t i = base + (size_t)t * DREC;
    f16 z2[2]; *(uint32_t*)z2 = *(const uint32_t*)(z + i);
    u16 x2[2]; *(uint32_t*)x2 = *(const uint32_t*)(xin + i);
    u16 g2[2]; *(uint32_t*)g2 = *(const uint32_t*)(gate_y + i);
    float a0 = sigm((float)z2[0]), a1 = sigm((float)z2[1]);
    h.x = a0 * h.x + sqrtf(1.f - a0 * a0 + 1e-8f) * b2f(x2[0]);
    h.y = a1 * h.y + sqrtf(1.f - a1 * a1 + 1e-8f) * b2f(x2[1]);
    u16 o2[2];
    o2[0] = f2bf(b2f(g2[0]) * h.x);
    o2[1] = f2bf(b2f(g2[1]) * h.y);
    *(uint32_t*)(gate_y + i) = *(uint32_t*)o2;
  }
}

// ---------------------------------------------------------------------------
extern "C" void kernel_launch(void* const* d_in, const int* in_sizes, int n_in,
                              void* d_out, int out_size, void* d_ws, size_t ws_size,
                              hipStream_t stream) {
  const float* x      = (const float*)d_in[0];
  const float* ln1    = (const float*)d_in[1];
  const float* ln2    = (const float*)d_in[2];
  const float* w_in   = (const float*)d_in[3];
  const float* w_gate = (const float*)d_in[4];
  const float* a_par  = (const float*)d_in[5];
  const float* w_a    = (const float*)d_in[6];
  const float* w_out  = (const float*)d_in[7];
  const float* w_mg   = (const float*)d_in[8];
  const float* w_mu   = (const float*)d_in[9];
  const float* w_md   = (const float*)d_in[10];
  float* out = (float*)d_out;
  char* ws = (char*)d_ws;

  const size_t MB = 1024ull * 1024ull;
  u16* wb_in  = (u16*)(ws + 0 * MB);
  u16* wb_gt  = (u16*)(ws + 4 * MB);
  u16* wb_a   = (u16*)(ws + 8 * MB);
  u16* wb_out = (u16*)(ws + 16 * MB);
  u16* wb_mg  = (u16*)(ws + 20 * MB);
  u16* wb_mu  = (u16*)(ws + 28 * MB);
  u16* wb_md  = (u16*)(ws + 36 * MB);
  u16* hbuf  = (u16*)(ws + 44 * MB);
  f16* zbuf  = (f16*)(ws + 44 * MB);
  u16* gateb = (u16*)(ws + 108 * MB);
  u16* mbuf  = (u16*)(ws + 108 * MB);
  float2* chh = (float2*)(ws + 0 * MB);
  float2* chp = (float2*)(ws + 2 * MB);
  u16* xinb = (u16*)d_out;

  // 1) all weights -> bf16
  f2b_all<<<22528, 256, 0, stream>>>(w_in, w_gate, w_a, w_out, w_mg, w_mu, w_md,
                                     wb_in, wb_gt, wb_a, wb_out, wb_mg, wb_mu, wb_md);

  // 2) h = rmsnorm(x, ln1)
  rmsnorm_kernel<<<BT, 256, 0, stream>>>(x, ln1, hbuf);

  // 3) fused: xin = h@w_in^T (raw -> d_out), gate = sigmoid(h@w_gate^T)
  gemm256d<EPI2_XG><<<dim3(BT / 256, DREC / 128), 512, 0, stream>>>(
      hbuf, wb_in, wb_gt, HID, DREC, HID, HID, xinb, gateb);

  // 4) z = a_param + xin@w_a^T (fp16 logits)
  gemm256<EPI_LOGIT><<<dim3(BT / 256, DREC / 256), 512, 0, stream>>>(
      xinb, wb_a, DREC, DREC, DREC, DREC, nullptr, zbuf, a_par);

  // 5) chunked scan; y = gate*h in place over gate
  scan_phase1<<<NCH * NPAIR / 256, 256, 0, stream>>>(zbuf, xinb, chh, chp);
  scan_phase2<<<NPAIR / 256, 256, 0, stream>>>(chh, chp);
  scan_phase3<<<NCH * NPAIR / 256, 256, 0, stream>>>(zbuf, xinb, gateb, chh);

  // 6) xr = x + y@w_out^T -> d_out (xin dead)
  gemm256<EPI_ADDF><<<dim3(BT / 256, HID / 256), 512, 0, stream>>>(
      gateb, wb_out, DREC, HID, DREC, DREC, out, nullptr, x);

  // 7) h2 = rmsnorm(xr, ln2)
  rmsnorm_kernel<<<BT, 256, 0, stream>>>(out, ln2, hbuf);

  // 8) MLP in two INTER halves; down-GEMM accumulates into d_out in place
  for (int half = 0; half < 2; ++half) {
    const u16* wmg_h = wb_mg + (size_t)half * 2048 * HID;
    const u16* wmu_h = wb_mu + (size_t)half * 2048 * HID;
    const u16* wmd_h = wb_md + (size_t)half * 2048;      // column slice, ldW=INTER
    gemm256d<EPI2_SM><<<dim3(BT / 256, 2048 / 128), 512, 0, stream>>>(
        hbuf, wmg_h, wmu_h, HID, 2048, HID, HID, mbuf, nullptr);
    gemm256<EPI_ADDF><<<dim3(BT / 256, HID / 256), 512, 0, stream>>>(
        mbuf, wmd_h, 2048, HID, 2048, INTER, out, nullptr, out);
  }
}

// Round 2
// 1210.178 us; speedup vs baseline: 1.0264x; 1.0264x over previous
//
#include <hip/hip_runtime.h>
#include <cstdint>
#include <cmath>

// ---------------------------------------------------------------------------
// HawkBlock on MI355X (gfx950). Round 6.
// R5 post-mortem: 8-phase port regressed (835 TF, MfmaUtil 34%) because the
// counted wait VMC(4) drained loads issued only 3 phases (~465 cyc) earlier —
// shallower than load latency -> behaved like drain-0 (m218: counted vs
// drain0 = +38%; 835*1.38 = m198's 1167). R6: derived-waits fix. Stage the
// FULL tile t+2 during tile t (B-halves at ph3, A-halves at ph4 — earliest
// legal points per region-lifetime analysis: B region free after ph2, A after
// ph3), steady-state depth 16 vmcnt units, VMC(8) once per K-tile at ph4;
// youngest drained load now 4+ phases old (>=620 cyc, self-correcting).
// Dual variant: B0 free after ph1 -> stage ph2, B1 after ph2 -> ph3, A -> ph4.
// Prologue: tile0 (8u) + tile1 (8u), VMC(8) == loop steady state.
// Everything else (scan / rmsnorm / f2b / epilogues / swizzle) unchanged.
// ---------------------------------------------------------------------------

typedef unsigned short u16;
typedef _Float16 f16;
typedef __bf16 bf16x8 __attribute__((ext_vector_type(8)));
typedef float  f32x4  __attribute__((ext_vector_type(4)));

#define HID   1024
#define DREC  2048
#define INTER 4096
#define BT    16384   // B*T rows
#define TLEN  4096
#define NCHAN 8192    // B * DREC
#define CHUNK 64
#define NCH   64      // TLEN / CHUNK
#define NPAIR 4096    // NCHAN/2 channel pairs

__device__ __forceinline__ float b2f(u16 u) {
  union { unsigned int i; float f; } v; v.i = ((unsigned int)u) << 16; return v.f;
}
__device__ __forceinline__ u16 f2bf(float f) {  // RNE
  unsigned int u = __builtin_bit_cast(unsigned int, f);
  u += 0x7FFFu + ((u >> 16) & 1u);
  return (u16)(u >> 16);
}
__device__ __forceinline__ float sigm(float x) { return 1.f / (1.f + expf(-x)); }

typedef __attribute__((address_space(1))) void as1_void;
typedef __attribute__((address_space(3))) void as3_void;
__device__ __forceinline__ void async16(const void* g, void* l) {
  __builtin_amdgcn_global_load_lds((as1_void*)g, (as3_void*)l, 16, 0, 0);
}

// Phase-discipline macros (rule #18: sched_barrier(0) after inline-asm waits).
#define BARSYNC() do { __builtin_amdgcn_s_barrier(); __builtin_amdgcn_sched_barrier(0); } while (0)
#define LGKM0()   do { asm volatile("s_waitcnt lgkmcnt(0)" ::: "memory"); __builtin_amdgcn_sched_barrier(0); } while (0)
#define VMC(N)    do { asm volatile("s_waitcnt vmcnt(" #N ")" ::: "memory"); __builtin_amdgcn_sched_barrier(0); } while (0)
#define FENCE()   do { asm volatile("" ::: "memory"); __builtin_amdgcn_sched_barrier(0); } while (0)

// ---------------------------------------------------------------------------
// All 7 weight conversions in ONE kernel (unchanged).
__global__ void f2b_all(const float* s0, const float* s1, const float* s2,
                        const float* s3, const float* s4, const float* s5,
                        const float* s6,
                        u16* d0, u16* d1, u16* d2, u16* d3, u16* d4, u16* d5,
                        u16* d6) {
  int blk = blockIdx.x;
  const float* src; u16* dst; int rel;
  if      (blk < 2048)  { src = s0; dst = d0; rel = blk; }
  else if (blk < 4096)  { src = s1; dst = d1; rel = blk - 2048; }
  else if (blk < 8192)  { src = s2; dst = d2; rel = blk - 4096; }
  else if (blk < 10240) { src = s3; dst = d3; rel = blk - 8192; }
  else if (blk < 14336) { src = s4; dst = d4; rel = blk - 10240; }
  else if (blk < 18432) { src = s5; dst = d5; rel = blk - 14336; }
  else                  { src = s6; dst = d6; rel = blk - 18432; }
  int i = rel * 256 + threadIdx.x;
  float4 v = ((const float4*)src)[i];
  ushort4 o;
  o.x = f2bf(v.x); o.y = f2bf(v.y); o.z = f2bf(v.z); o.w = f2bf(v.w);
  ((ushort4*)dst)[i] = o;
}

// rmsnorm over rows of 1024 fp32, bf16 out (unchanged).
__global__ void rmsnorm_kernel(const float* __restrict__ x, const float* __restrict__ w,
                               u16* __restrict__ out) {
  const int row = blockIdx.x;
  const int tid = threadIdx.x;
  float4 v = ((const float4*)(x + (size_t)row * HID))[tid];
  float ss = v.x * v.x + v.y * v.y + v.z * v.z + v.w * v.w;
#pragma unroll
  for (int o = 32; o > 0; o >>= 1) ss += __shfl_down(ss, o);
  __shared__ float red[4];
  const int lane = tid & 63, wv = tid >> 6;
  if (lane == 0) red[wv] = ss;
  __syncthreads();
  float tot = red[0] + red[1] + red[2] + red[3];
  float sc = rsqrtf(tot * (1.f / (float)HID) + 1e-6f);
  float4 wv4 = ((const float4*)w)[tid];
  ushort4 o;
  o.x = f2bf(v.x * sc * wv4.x); o.y = f2bf(v.y * sc * wv4.y);
  o.z = f2bf(v.z * sc * wv4.z); o.w = f2bf(v.w * sc * wv4.w);
  ((ushort4*)(out + (size_t)row * HID))[tid] = o;
}

// ---------------------------------------------------------------------------
// 256-tile GEMM building blocks.
// Half-tile = 128 rows x 64 cols bf16 = 16KB; staged by 512 threads x 2 x
// global_load_lds_dwordx4 (= 2 vmcnt units per wave). Chunk-XOR swizzle
// (conflict-free per R4/R5 counters) on the pre-swizzled GLOBAL source; LDS
// dest linear as global_load_lds requires.
__device__ __forceinline__ void stageG(const u16* __restrict__ g, int ldg,
                                       int rb, int k0, u16* lbase, int tid) {
#pragma unroll
  for (int i = 0; i < 2; ++i) {
    int p = i * 512 + tid;          // 16B-chunk index in [0,1024)
    int r = p >> 3;                 // local row 0..127
    int sg = (p & 7) ^ (r & 7);     // swizzled source chunk
    async16(g + (size_t)(rb + r) * ldg + (k0 + sg * 8), (char*)lbase + p * 16);
  }
}

// 4 M-fragments, both k-subtiles: 8 x ds_read_b128.
__device__ __forceinline__ void readA4(bf16x8 (&af)[4][2], const u16* base,
                                       int rbase, int quad) {
#pragma unroll
  for (int i = 0; i < 4; ++i) {
    int r = rbase + i * 16;
#pragma unroll
    for (int ks = 0; ks < 2; ++ks)
      af[i][ks] = ((const bf16x8*)base)[r * 8 + ((ks * 4 + quad) ^ (r & 7))];
  }
}
// 2 N-fragments, both k-subtiles: 4 x ds_read_b128.
__device__ __forceinline__ void readB2(bf16x8 (&bf)[2][2], const u16* base,
                                       int rbase, int quad) {
#pragma unroll
  for (int i = 0; i < 2; ++i) {
    int r = rbase + i * 16;
#pragma unroll
    for (int ks = 0; ks < 2; ++ks)
      bf[i][ks] = ((const bf16x8*)base)[r * 8 + ((ks * 4 + quad) ^ (r & 7))];
  }
}

// One C-quadrant: 16 MFMA under setprio(1) (T5). Static indices (rule #20).
template <int MI0, int NI0, int NA>
__device__ __forceinline__ void mfmaQ(f32x4 (&acc)[8][NA],
                                      const bf16x8 (&af)[4][2],
                                      const bf16x8 (&bf)[2][2]) {
  __builtin_amdgcn_s_setprio(1);
#pragma unroll
  for (int mi = 0; mi < 4; ++mi)
#pragma unroll
    for (int ni = 0; ni < 2; ++ni)
#pragma unroll
      for (int ks = 0; ks < 2; ++ks)
        acc[MI0 + mi][NI0 + ni] = __builtin_amdgcn_mfma_f32_16x16x32_bf16(
            af[mi][ks], bf[ni][ks], acc[MI0 + mi][NI0 + ni], 0, 0, 0);
  __builtin_amdgcn_s_setprio(0);
}

// ---------------------------------------------------------------------------
// Single-B 256x256 GEMM, 8 waves (2Mx4N), wave tile 128x64. Phases per K-tile
// t (buf b=t&1), derived-waits schedule:
//   ph1: ds af-low + bfL;                          MFMA Q(0,lo)
//   ph2: ds bfH;                                   MFMA Q(0,hi)
//   ph3: ds af-high; stage B0,B1(t+2)->sB[b];      MFMA Q(1,hi)
//   ph4:             stage A0,A1(t+2)->sA[b];      MFMA Q(1,lo); VMC(8)
// Region lifetimes: full B region last read ph2 (bfL/bfH both span B0,B1),
// full A region last read ph3 -> t+2 staging at ph3/ph4 is the earliest legal.
// Steady state: 16 units outstanding at VMC(8) -> drains tile t+1, whose
// youngest load (A@ph4(t-1)) is 4 phases (~620+ cyc) old.
enum { EPI_LOGIT = 0, EPI_ADDF = 1 };

template <int EPI>
__global__ __launch_bounds__(512, 2)
void gemm256(const u16* __restrict__ A, const u16* __restrict__ W,
             int K, int N, int ldA, int ldW,
             float* outf, f16* outz, const float* auxf) {
  __shared__ u16 sA[2][16384];   // [buf][256 rows x 64 cols]
  __shared__ u16 sB[2][16384];
  const int tid  = threadIdx.x;
  const int lane = tid & 63, wv = tid >> 6;
  const int wm   = wv >> 2, wn = wv & 3;
  const int lm   = lane & 15, quad = lane >> 4;
  const int row0 = blockIdx.x * 256, col0 = blockIdx.y * 256;
  const int NT   = K >> 6;

  f32x4 acc[8][4];
#pragma unroll
  for (int i = 0; i < 8; ++i)
#pragma unroll
    for (int j = 0; j < 4; ++j) acc[i][j] = (f32x4)0.f;

  // Prologue: tile0 (8u), then tile1 (8u), VMC(8) -> tile0 landed, 8u in
  // flight == loop steady state.
  stageG(W, ldW, col0,       0, sB[0],        tid);
  stageG(W, ldW, col0 + 128, 0, sB[0] + 8192, tid);
  stageG(A, ldA, row0,       0, sA[0],        tid);
  stageG(A, ldA, row0 + 128, 0, sA[0] + 8192, tid);
  FENCE();
  if (NT > 1) {
    stageG(W, ldW, col0,       64, sB[1],        tid);
    stageG(W, ldW, col0 + 128, 64, sB[1] + 8192, tid);
    stageG(A, ldA, row0,       64, sA[1],        tid);
    stageG(A, ldA, row0 + 128, 64, sA[1] + 8192, tid);
    VMC(8);
  } else {
    VMC(0);
  }
  BARSYNC();

  for (int t = 0; t < NT; ++t) {
    const int b = t & 1;
    const u16* Ab = sA[b];
    const u16* Bb = sB[b];
    bf16x8 af[4][2], bfL[2][2], bfH[2][2];
    const int kN = (t + 2) * 64;          // K-offset of tile t+2

    // ---- phase 1 ----
    readA4(af, Ab, wm * 128 + lm, quad);
    readB2(bfL, Bb, wn * 64 + lm, quad);
    BARSYNC(); LGKM0();
    mfmaQ<0, 0>(acc, af, bfL);
    BARSYNC();

    // ---- phase 2 ----
    readB2(bfH, Bb, wn * 64 + 32 + lm, quad);
    BARSYNC(); LGKM0();
    mfmaQ<0, 2>(acc, af, bfH);
    BARSYNC();

    // ---- phase 3 ---- (B region of buf b free after ph2)
    readA4(af, Ab, wm * 128 + 64 + lm, quad);
    if (t + 2 < NT) {
      stageG(W, ldW, col0,       kN, (u16*)sB[b],        tid);
      stageG(W, ldW, col0 + 128, kN, (u16*)sB[b] + 8192, tid);
    }
    BARSYNC(); LGKM0();
    mfmaQ<4, 2>(acc, af, bfH);
    BARSYNC();

    // ---- phase 4 ---- (A region of buf b free after ph3)
    if (t + 2 < NT) {
      stageG(A, ldA, row0,       kN, (u16*)sA[b],        tid);
      stageG(A, ldA, row0 + 128, kN, (u16*)sA[b] + 8192, tid);
    }
    mfmaQ<4, 0>(acc, af, bfL);
    if (t + 2 < NT) { VMC(8); } else { VMC(0); }
    BARSYNC();
  }

  // Epilogue. C/D layout: col = lane&15, row = quad*4 + reg (m89/m91).
#pragma unroll
  for (int mi = 0; mi < 8; ++mi) {
    const int rb = row0 + wm * 128 + mi * 16 + quad * 4;
#pragma unroll
    for (int ni = 0; ni < 4; ++ni) {
      const int cg = col0 + wn * 64 + ni * 16 + lm;
      f32x4 v = acc[mi][ni];
#pragma unroll
      for (int rr = 0; rr < 4; ++rr) {
        size_t idx = (size_t)(rb + rr) * N + cg;
        if constexpr (EPI == EPI_LOGIT) {
          outz[idx] = (f16)(v[rr] + auxf[cg]);   // pre-sigmoid logit, fp16
        } else {
          outf[idx] = v[rr] + auxf[idx];         // residual add; auxf may == outf
        }
      }
    }
  }
}

// ---------------------------------------------------------------------------
// Dual-B 256x128 GEMM (same schedule). Region lifetimes differ: B0 (matrix0)
// last read ph1 -> stage t+2 at ph2; B1 (matrix1) last read ph2 -> ph3;
// A last read ph3 -> ph4. Same VMC(8) at ph4 (16u outstanding, drains t+1).
enum { EPI2_XG = 0, EPI2_SM = 1 };

template <int EPI>
__global__ __launch_bounds__(512, 2)
void gemm256d(const u16* __restrict__ A, const u16* __restrict__ W0,
              const u16* __restrict__ W1,
              int K, int N, int ldA, int ldW,
              u16* out0, u16* out1) {
  __shared__ u16 sA[2][16384];   // [buf][256 x 64]
  __shared__ u16 sB[2][16384];   // [buf][matrix0 128x64 | matrix1 128x64]
  const int tid  = threadIdx.x;
  const int lane = tid & 63, wv = tid >> 6;
  const int wm   = wv >> 2, wn = wv & 3;
  const int lm   = lane & 15, quad = lane >> 4;
  const int row0 = blockIdx.x * 256, col0 = blockIdx.y * 128;
  const int NT   = K >> 6;

  f32x4 acc0[8][2], acc1[8][2];
#pragma unroll
  for (int i = 0; i < 8; ++i)
#pragma unroll
    for (int j = 0; j < 2; ++j) { acc0[i][j] = (f32x4)0.f; acc1[i][j] = (f32x4)0.f; }

  stageG(W0, ldW, col0,       0, sB[0],        tid);
  stageG(W1, ldW, col0,       0, sB[0] + 8192, tid);
  stageG(A,  ldA, row0,       0, sA[0],        tid);
  stageG(A,  ldA, row0 + 128, 0, sA[0] + 8192, tid);
  FENCE();
  if (NT > 1) {
    stageG(W0, ldW, col0,       64, sB[1],        tid);
    stageG(W1, ldW, col0,       64, sB[1] + 8192, tid);
    stageG(A,  ldA, row0,       64, sA[1],        tid);
    stageG(A,  ldA, row0 + 128, 64, sA[1] + 8192, tid);
    VMC(8);
  } else {
    VMC(0);
  }
  BARSYNC();

  for (int t = 0; t < NT; ++t) {
    const int b = t & 1;
    const u16* Ab = sA[b];
    const u16* Bb = sB[b];
    bf16x8 af[4][2], bf0[2][2], bf1[2][2];
    const int kN = (t + 2) * 64;

    // ---- phase 1 ----
    readA4(af, Ab, wm * 128 + lm, quad);
    readB2(bf0, Bb, wn * 32 + lm, quad);
    BARSYNC(); LGKM0();
    mfmaQ<0, 0>(acc0, af, bf0);
    BARSYNC();

    // ---- phase 2 ---- (B0 region free after ph1)
    readB2(bf1, Bb + 8192, wn * 32 + lm, quad);
    if (t + 2 < NT) stageG(W0, ldW, col0, kN, (u16*)sB[b], tid);
    BARSYNC(); LGKM0();
    mfmaQ<0, 0>(acc1, af, bf1);
    BARSYNC();

    // ---- phase 3 ---- (B1 region free after ph2)
    readA4(af, Ab, wm * 128 + 64 + lm, quad);
    if (t + 2 < NT) stageG(W1, ldW, col0, kN, (u16*)sB[b] + 8192, tid);
    BARSYNC(); LGKM0();
    mfmaQ<4, 0>(acc1, af, bf1);
    BARSYNC();

    // ---- phase 4 ---- (A region free after ph3)
    if (t + 2 < NT) {
      stageG(A, ldA, row0,       kN, (u16*)sA[b],        tid);
      stageG(A, ldA, row0 + 128, kN, (u16*)sA[b] + 8192, tid);
    }
    mfmaQ<4, 0>(acc0, af, bf0);
    if (t + 2 < NT) { VMC(8); } else { VMC(0); }
    BARSYNC();
  }

#pragma unroll
  for (int mi = 0; mi < 8; ++mi) {
    const int rb = row0 + wm * 128 + mi * 16 + quad * 4;
#pragma unroll
    for (int ni = 0; ni < 2; ++ni) {
      const int cg = col0 + wn * 32 + ni * 16 + lm;
#pragma unroll
      for (int rr = 0; rr < 4; ++rr) {
        size_t idx = (size_t)(rb + rr) * N + cg;
        float v0 = acc0[mi][ni][rr];
        float v1 = acc1[mi][ni][rr];
        if constexpr (EPI == EPI2_XG) {
          out0[idx] = f2bf(v0);                 // xin raw
          out1[idx] = f2bf(sigm(v1));           // gate
        } else {
          out0[idx] = f2bf(v0 * sigm(v0) * v1); // m = silu(g) * u
        }
      }
    }
  }
}

// ---------------------------------------------------------------------------
// Chunked scan (unchanged).
__global__ void scan_phase1(const f16* __restrict__ z, const u16* __restrict__ xin,
                            float2* __restrict__ ch_h, float2* __restrict__ ch_p) {
  int gtid = blockIdx.x * 256 + threadIdx.x;
  int c = gtid >> 12;
  int pair = gtid & (NPAIR - 1);
  int b = pair >> 10;
  int d = (pair & 1023) * 2;
  size_t base = ((size_t)b * TLEN + (size_t)c * CHUNK) * DREC + d;
  float2 h = {0.f, 0.f}, P = {1.f, 1.f};
#pragma unroll 8
  for (int t = 0; t < CHUNK; ++t) {
    size_t i = base + (size_t)t * DREC;
    f16 z2[2]; *(uint32_t*)z2 = *(const uint32_t*)(z + i);
    u16 x2[2]; *(uint32_t*)x2 = *(const uint32_t*)(xin + i);
    float a0 = sigm((float)z2[0]), a1 = sigm((float)z2[1]);
    h.x = a0 * h.x + sqrtf(1.f - a0 * a0 + 1e-8f) * b2f(x2[0]);
    h.y = a1 * h.y + sqrtf(1.f - a1 * a1 + 1e-8f) * b2f(x2[1]);
    P.x *= a0; P.y *= a1;
  }
  ch_h[gtid] = h;
  ch_p[gtid] = P;
}

__global__ void scan_phase2(float2* __restrict__ ch_h, const float2* __restrict__ ch_p) {
  int pair = blockIdx.x * 256 + threadIdx.x;
  float2 H = {0.f, 0.f};
#pragma unroll
  for (int c = 0; c < NCH; ++c) {
    int i = c * NPAIR + pair;
    float2 he = ch_h[i];
    float2 P  = ch_p[i];
    ch_h[i] = H;
    H.x = he.x + P.x * H.x;
    H.y = he.y + P.y * H.y;
  }
}

__global__ void scan_phase3(const f16* __restrict__ z, const u16* __restrict__ xin,
                            u16* gate_y, const float2* __restrict__ ch_h) {
  int gtid = blockIdx.x * 256 + threadIdx.x;
  int c = gtid >> 12;
  int pair = gtid & (NPAIR - 1);
  int b = pair >> 10;
  int d = (pair & 1023) * 2;
  size_t base = ((size_t)b * TLEN + (size_t)c * CHUNK) * DREC + d;
  float2 h = ch_h[gtid];
#pragma unroll 8
  for (int t = 0; t < CHUNK; ++t) {
    size_t i = base + (size_t)t * DREC;
    f16 z2[2]; *(uint32_t*)z2 = *(const uint32_t*)(z + i);
    u16 x2[2]; *(uint32_t*)x2 = *(const uint32_t*)(xin + i);
    u16 g2[2]; *(uint32_t*)g2 = *(const uint32_t*)(gate_y + i);
    float a0 = sigm((float)z2[0]), a1 = sigm((float)z2[1]);
    h.x = a0 * h.x + sqrtf(1.f - a0 * a0 + 1e-8f) * b2f(x2[0]);
    h.y = a1 * h.y + sqrtf(1.f - a1 * a1 + 1e-8f) * b2f(x2[1]);
    u16 o2[2];
    o2[0] = f2bf(b2f(g2[0]) * h.x);
    o2[1] = f2bf(b2f(g2[1]) * h.y);
    *(uint32_t*)(gate_y + i) = *(uint32_t*)o2;
  }
}

// ---------------------------------------------------------------------------
extern "C" void kernel_launch(void* const* d_in, const int* in_sizes, int n_in,
                              void* d_out, int out_size, void* d_ws, size_t ws_size,
                              hipStream_t stream) {
  const float* x      = (const float*)d_in[0];
  const float* ln1    = (const float*)d_in[1];
  const float* ln2    = (const float*)d_in[2];
  const float* w_in   = (const float*)d_in[3];
  const float* w_gate = (const float*)d_in[4];
  const float* a_par  = (const float*)d_in[5];
  const float* w_a    = (const float*)d_in[6];
  const float* w_out  = (const float*)d_in[7];
  const float* w_mg   = (const float*)d_in[8];
  const float* w_mu   = (const float*)d_in[9];
  const float* w_md   = (const float*)d_in[10];
  float* out = (float*)d_out;
  char* ws = (char*)d_ws;

  const size_t MB = 1024ull * 1024ull;
  u16* wb_in  = (u16*)(ws + 0 * MB);
  u16* wb_gt  = (u16*)(ws + 4 * MB);
  u16* wb_a   = (u16*)(ws + 8 * MB);
  u16* wb_out = (u16*)(ws + 16 * MB);
  u16* wb_mg  = (u16*)(ws + 20 * MB);
  u16* wb_mu  = (u16*)(ws + 28 * MB);
  u16* wb_md  = (u16*)(ws + 36 * MB);
  u16* hbuf  = (u16*)(ws + 44 * MB);
  f16* zbuf  = (f16*)(ws + 44 * MB);
  u16* gateb = (u16*)(ws + 108 * MB);
  u16* mbuf  = (u16*)(ws + 108 * MB);
  float2* chh = (float2*)(ws + 0 * MB);
  float2* chp = (float2*)(ws + 2 * MB);
  u16* xinb = (u16*)d_out;

  // 1) all weights -> bf16
  f2b_all<<<22528, 256, 0, stream>>>(w_in, w_gate, w_a, w_out, w_mg, w_mu, w_md,
                                     wb_in, wb_gt, wb_a, wb_out, wb_mg, wb_mu, wb_md);

  // 2) h = rmsnorm(x, ln1)
  rmsnorm_kernel<<<BT, 256, 0, stream>>>(x, ln1, hbuf);

  // 3) fused: xin = h@w_in^T (raw -> d_out), gate = sigmoid(h@w_gate^T)
  gemm256d<EPI2_XG><<<dim3(BT / 256, DREC / 128), 512, 0, stream>>>(
      hbuf, wb_in, wb_gt, HID, DREC, HID, HID, xinb, gateb);

  // 4) z = a_param + xin@w_a^T (fp16 logits)
  gemm256<EPI_LOGIT><<<dim3(BT / 256, DREC / 256), 512, 0, stream>>>(
      xinb, wb_a, DREC, DREC, DREC, DREC, nullptr, zbuf, a_par);

  // 5) chunked scan; y = gate*h in place over gate
  scan_phase1<<<NCH * NPAIR / 256, 256, 0, stream>>>(zbuf, xinb, chh, chp);
  scan_phase2<<<NPAIR / 256, 256, 0, stream>>>(chh, chp);
  scan_phase3<<<NCH * NPAIR / 256, 256, 0, stream>>>(zbuf, xinb, gateb, chh);

  // 6) xr = x + y@w_out^T -> d_out (xin dead)
  gemm256<EPI_ADDF><<<dim3(BT / 256, HID / 256), 512, 0, stream>>>(
      gateb, wb_out, DREC, HID, DREC, DREC, out, nullptr, x);

  // 7) h2 = rmsnorm(xr, ln2)
  rmsnorm_kernel<<<BT, 256, 0, stream>>>(out, ln2, hbuf);

  // 8) MLP in two INTER halves; down-GEMM accumulates into d_out in place
  for (int half = 0; half < 2; ++half) {
    const u16* wmg_h = wb_mg + (size_t)half * 2048 * HID;
    const u16* wmu_h = wb_mu + (size_t)half * 2048 * HID;
    const u16* wmd_h = wb_md + (size_t)half * 2048;      // column slice, ldW=INTER
    gemm256d<EPI2_SM><<<dim3(BT / 256, 2048 / 64 / 2), 512, 0, stream>>>(
        hbuf, wmg_h, wmu_h, HID, 2048, HID, HID, mbuf, nullptr);
    gemm256<EPI_ADDF><<<dim3(BT / 256, HID / 256), 512, 0, stream>>>(
        mbuf, wmd_h, 2048, HID, 2048, INTER, out, nullptr, out);
  }
}

// Round 3
// 1191.693 us; speedup vs baseline: 1.0423x; 1.0155x over previous
//
#include <hip/hip_runtime.h>
#include <cstdint>
#include <cmath>

// ---------------------------------------------------------------------------
// HawkBlock on MI355X (gfx950). Round 7.
// R6 post-mortem: vmcnt depth was not the stall (34->35% MfmaUtil). Cycle
// accounting: K-tile 6200 cyc vs MFMA 2480 + LDS 2000 — the 4-phase lockstep
// (reads -> barrier -> lgkm0 -> MFMA -> barrier, x4) serializes the LDS and
// matrix pipes and pays 8 barriers/tile; sched_barrier spam kept VALUBusy 33%.
// R7: issue ALL 24 ds_reads of the tile up front and let the compiler emit
// counted lgkm waits (m97: it does this well) so reads service under earlier
// MFMA quadrants; barriers only at the 3 write-after-read hazard points
// (B-region free, A-region free, tile boundary). VMC(8) arithmetic unchanged
// (16 outstanding at wait -> drains tile t+1, issued a full tile earlier).
// Scan / rmsnorm / f2b / epilogues / swizzle unchanged.
// ---------------------------------------------------------------------------

typedef unsigned short u16;
typedef _Float16 f16;
typedef __bf16 bf16x8 __attribute__((ext_vector_type(8)));
typedef float  f32x4  __attribute__((ext_vector_type(4)));

#define HID   1024
#define DREC  2048
#define INTER 4096
#define BT    16384   // B*T rows
#define TLEN  4096
#define NCHAN 8192    // B * DREC
#define CHUNK 64
#define NCH   64      // TLEN / CHUNK
#define NPAIR 4096    // NCHAN/2 channel pairs

__device__ __forceinline__ float b2f(u16 u) {
  union { unsigned int i; float f; } v; v.i = ((unsigned int)u) << 16; return v.f;
}
__device__ __forceinline__ u16 f2bf(float f) {  // RNE
  unsigned int u = __builtin_bit_cast(unsigned int, f);
  u += 0x7FFFu + ((u >> 16) & 1u);
  return (u16)(u >> 16);
}
__device__ __forceinline__ float sigm(float x) { return 1.f / (1.f + expf(-x)); }

typedef __attribute__((address_space(1))) void as1_void;
typedef __attribute__((address_space(3))) void as3_void;
__device__ __forceinline__ void async16(const void* g, void* l) {
  __builtin_amdgcn_global_load_lds((as1_void*)g, (as3_void*)l, 16, 0, 0);
}

// Sync macros. sched_barrier(0) pins stages/reads to their side of each sync
// point; everything between sync points is left to the compiler (it inserts
// counted lgkmcnt for ds_read->MFMA deps and CSEs addressing).
#define BARSYNC() do { __builtin_amdgcn_s_barrier(); __builtin_amdgcn_sched_barrier(0); } while (0)
#define VMC(N)    do { asm volatile("s_waitcnt vmcnt(" #N ")" ::: "memory"); __builtin_amdgcn_sched_barrier(0); } while (0)
#define FENCE()   do { asm volatile("" ::: "memory"); __builtin_amdgcn_sched_barrier(0); } while (0)

// ---------------------------------------------------------------------------
// All 7 weight conversions in ONE kernel (unchanged).
__global__ void f2b_all(const float* s0, const float* s1, const float* s2,
                        const float* s3, const float* s4, const float* s5,
                        const float* s6,
                        u16* d0, u16* d1, u16* d2, u16* d3, u16* d4, u16* d5,
                        u16* d6) {
  int blk = blockIdx.x;
  const float* src; u16* dst; int rel;
  if      (blk < 2048)  { src = s0; dst = d0; rel = blk; }
  else if (blk < 4096)  { src = s1; dst = d1; rel = blk - 2048; }
  else if (blk < 8192)  { src = s2; dst = d2; rel = blk - 4096; }
  else if (blk < 10240) { src = s3; dst = d3; rel = blk - 8192; }
  else if (blk < 14336) { src = s4; dst = d4; rel = blk - 10240; }
  else if (blk < 18432) { src = s5; dst = d5; rel = blk - 14336; }
  else                  { src = s6; dst = d6; rel = blk - 18432; }
  int i = rel * 256 + threadIdx.x;
  float4 v = ((const float4*)src)[i];
  ushort4 o;
  o.x = f2bf(v.x); o.y = f2bf(v.y); o.z = f2bf(v.z); o.w = f2bf(v.w);
  ((ushort4*)dst)[i] = o;
}

// rmsnorm over rows of 1024 fp32, bf16 out (unchanged).
__global__ void rmsnorm_kernel(const float* __restrict__ x, const float* __restrict__ w,
                               u16* __restrict__ out) {
  const int row = blockIdx.x;
  const int tid = threadIdx.x;
  float4 v = ((const float4*)(x + (size_t)row * HID))[tid];
  float ss = v.x * v.x + v.y * v.y + v.z * v.z + v.w * v.w;
#pragma unroll
  for (int o = 32; o > 0; o >>= 1) ss += __shfl_down(ss, o);
  __shared__ float red[4];
  const int lane = tid & 63, wv = tid >> 6;
  if (lane == 0) red[wv] = ss;
  __syncthreads();
  float tot = red[0] + red[1] + red[2] + red[3];
  float sc = rsqrtf(tot * (1.f / (float)HID) + 1e-6f);
  float4 wv4 = ((const float4*)w)[tid];
  ushort4 o;
  o.x = f2bf(v.x * sc * wv4.x); o.y = f2bf(v.y * sc * wv4.y);
  o.z = f2bf(v.z * sc * wv4.z); o.w = f2bf(v.w * sc * wv4.w);
  ((ushort4*)(out + (size_t)row * HID))[tid] = o;
}

// ---------------------------------------------------------------------------
// 256-tile GEMM building blocks. Half-tile = 128x64 bf16 = 16KB, staged by
// 512 threads x 2 async16 (= 2 vmcnt units/wave). Chunk-XOR swizzle on the
// pre-swizzled GLOBAL source (conflict-free per R4-R6 counters); LDS dest
// linear as global_load_lds requires.
__device__ __forceinline__ void stageG(const u16* __restrict__ g, int ldg,
                                       int rb, int k0, u16* lbase, int tid) {
#pragma unroll
  for (int i = 0; i < 2; ++i) {
    int p = i * 512 + tid;          // 16B-chunk index in [0,1024)
    int r = p >> 3;                 // local row 0..127
    int sg = (p & 7) ^ (r & 7);     // swizzled source chunk
    async16(g + (size_t)(rb + r) * ldg + (k0 + sg * 8), (char*)lbase + p * 16);
  }
}

// 4 M-fragments, both k-subtiles: 8 x ds_read_b128.
__device__ __forceinline__ void readA4(bf16x8 (&af)[4][2], const u16* base,
                                       int rbase, int quad) {
#pragma unroll
  for (int i = 0; i < 4; ++i) {
    int r = rbase + i * 16;
#pragma unroll
    for (int ks = 0; ks < 2; ++ks)
      af[i][ks] = ((const bf16x8*)base)[r * 8 + ((ks * 4 + quad) ^ (r & 7))];
  }
}
// 2 N-fragments, both k-subtiles: 4 x ds_read_b128.
__device__ __forceinline__ void readB2(bf16x8 (&bf)[2][2], const u16* base,
                                       int rbase, int quad) {
#pragma unroll
  for (int i = 0; i < 2; ++i) {
    int r = rbase + i * 16;
#pragma unroll
    for (int ks = 0; ks < 2; ++ks)
      bf[i][ks] = ((const bf16x8*)base)[r * 8 + ((ks * 4 + quad) ^ (r & 7))];
  }
}

// One C-quadrant: 16 MFMA under setprio(1) (T5). Static indices (rule #20).
template <int MI0, int NI0, int NA>
__device__ __forceinline__ void mfmaQ(f32x4 (&acc)[8][NA],
                                      const bf16x8 (&af)[4][2],
                                      const bf16x8 (&bf)[2][2]) {
  __builtin_amdgcn_s_setprio(1);
#pragma unroll
  for (int mi = 0; mi < 4; ++mi)
#pragma unroll
    for (int ni = 0; ni < 2; ++ni)
#pragma unroll
      for (int ks = 0; ks < 2; ++ks)
        acc[MI0 + mi][NI0 + ni] = __builtin_amdgcn_mfma_f32_16x16x32_bf16(
            af[mi][ks], bf[ni][ks], acc[MI0 + mi][NI0 + ni], 0, 0, 0);
  __builtin_amdgcn_s_setprio(0);
}

// ---------------------------------------------------------------------------
// Single-B 256x256 GEMM, 8 waves (2Mx4N), wave tile 128x64. Per K-tile t
// (buf b=t&1): issue all 24 ds_reads (afL,bfL,bfH,afH); quadrants Q(0,lo),
// Q(0,hi) consume B -> BAR1 -> stage B(t+2) into sB[b]; Q(1,hi) consumes afH
// -> BAR2 -> stage A(t+2) into sA[b]; Q(1,lo); VMC(8); BAR3.
// Hazards: BAR1 is after every wave consumed bfL/bfH (compiler lgkm waits
// guarantee read completion before consumption); BAR2 after afL/afH consumed.
// vmcnt: 8 units staged per tile; at VMC(8) outstanding = t+1's 8 + t+2's 8;
// drains tile t+1, issued a full tile (~4000+ cyc) earlier.
enum { EPI_LOGIT = 0, EPI_ADDF = 1 };

template <int EPI>
__global__ __launch_bounds__(512, 2)
void gemm256(const u16* __restrict__ A, const u16* __restrict__ W,
             int K, int N, int ldA, int ldW,
             float* outf, f16* outz, const float* auxf) {
  __shared__ u16 sA[2][16384];   // [buf][256 rows x 64 cols]
  __shared__ u16 sB[2][16384];
  const int tid  = threadIdx.x;
  const int lane = tid & 63, wv = tid >> 6;
  const int wm   = wv >> 2, wn = wv & 3;
  const int lm   = lane & 15, quad = lane >> 4;
  const int row0 = blockIdx.x * 256, col0 = blockIdx.y * 256;
  const int NT   = K >> 6;

  f32x4 acc[8][4];
#pragma unroll
  for (int i = 0; i < 8; ++i)
#pragma unroll
    for (int j = 0; j < 4; ++j) acc[i][j] = (f32x4)0.f;

  // Prologue: tile0 (8u) then tile1 (8u); VMC(8) -> tile0 landed, 8u in
  // flight == steady state.
  stageG(W, ldW, col0,       0, sB[0],        tid);
  stageG(W, ldW, col0 + 128, 0, sB[0] + 8192, tid);
  stageG(A, ldA, row0,       0, sA[0],        tid);
  stageG(A, ldA, row0 + 128, 0, sA[0] + 8192, tid);
  FENCE();
  if (NT > 1) {
    stageG(W, ldW, col0,       64, sB[1],        tid);
    stageG(W, ldW, col0 + 128, 64, sB[1] + 8192, tid);
    stageG(A, ldA, row0,       64, sA[1],        tid);
    stageG(A, ldA, row0 + 128, 64, sA[1] + 8192, tid);
    VMC(8);
  } else {
    VMC(0);
  }
  BARSYNC();

  for (int t = 0; t < NT; ++t) {
    const int b = t & 1;
    const u16* Ab = sA[b];
    const u16* Bb = sB[b];
    bf16x8 afL[4][2], afH[4][2], bfL[2][2], bfH[2][2];
    const int kN = (t + 2) * 64;          // K-offset of tile t+2

    // All tile-t ds_reads up front, in consumption order; compiler inserts
    // counted lgkm waits so later reads service under earlier MFMA quadrants.
    readA4(afL, Ab, wm * 128 + lm, quad);
    readB2(bfL, Bb, wn * 64 + lm, quad);
    readB2(bfH, Bb, wn * 64 + 32 + lm, quad);
    readA4(afH, Ab, wm * 128 + 64 + lm, quad);

    mfmaQ<0, 0>(acc, afL, bfL);
    mfmaQ<0, 2>(acc, afL, bfH);

    BARSYNC();                            // B region of buf b free
    if (t + 2 < NT) {
      stageG(W, ldW, col0,       kN, (u16*)sB[b],        tid);
      stageG(W, ldW, col0 + 128, kN, (u16*)sB[b] + 8192, tid);
    }
    mfmaQ<4, 2>(acc, afH, bfH);

    BARSYNC();                            // A region of buf b free
    if (t + 2 < NT) {
      stageG(A, ldA, row0,       kN, (u16*)sA[b],        tid);
      stageG(A, ldA, row0 + 128, kN, (u16*)sA[b] + 8192, tid);
    }
    mfmaQ<4, 0>(acc, afH, bfL);
    if (t + 2 < NT) { VMC(8); } else { VMC(0); }
    BARSYNC();
  }

  // Epilogue. C/D layout: col = lane&15, row = quad*4 + reg (m89/m91).
#pragma unroll
  for (int mi = 0; mi < 8; ++mi) {
    const int rb = row0 + wm * 128 + mi * 16 + quad * 4;
#pragma unroll
    for (int ni = 0; ni < 4; ++ni) {
      const int cg = col0 + wn * 64 + ni * 16 + lm;
      f32x4 v = acc[mi][ni];
#pragma unroll
      for (int rr = 0; rr < 4; ++rr) {
        size_t idx = (size_t)(rb + rr) * N + cg;
        if constexpr (EPI == EPI_LOGIT) {
          outz[idx] = (f16)(v[rr] + auxf[cg]);   // pre-sigmoid logit, fp16
        } else {
          outf[idx] = v[rr] + auxf[idx];         // residual add; auxf may == outf
        }
      }
    }
  }
}

// ---------------------------------------------------------------------------
// Dual-B 256x128 GEMM, same 3-barrier schedule. Quadrant order: acc0-lo
// (afL,bf0), acc1-lo (afL,bf1) -> BAR1 -> stage B0,B1(t+2) -> acc1-hi
// (afH,bf1) -> BAR2 -> stage A(t+2) -> acc0-hi (afH,bf0) -> VMC(8) -> BAR3.
enum { EPI2_XG = 0, EPI2_SM = 1 };

template <int EPI>
__global__ __launch_bounds__(512, 2)
void gemm256d(const u16* __restrict__ A, const u16* __restrict__ W0,
              const u16* __restrict__ W1,
              int K, int N, int ldA, int ldW,
              u16* out0, u16* out1) {
  __shared__ u16 sA[2][16384];   // [buf][256 x 64]
  __shared__ u16 sB[2][16384];   // [buf][matrix0 128x64 | matrix1 128x64]
  const int tid  = threadIdx.x;
  const int lane = tid & 63, wv = tid >> 6;
  const int wm   = wv >> 2, wn = wv & 3;
  const int lm   = lane & 15, quad = lane >> 4;
  const int row0 = blockIdx.x * 256, col0 = blockIdx.y * 128;
  const int NT   = K >> 6;

  f32x4 acc0[8][2], acc1[8][2];
#pragma unroll
  for (int i = 0; i < 8; ++i)
#pragma unroll
    for (int j = 0; j < 2; ++j) { acc0[i][j] = (f32x4)0.f; acc1[i][j] = (f32x4)0.f; }

  stageG(W0, ldW, col0,       0, sB[0],        tid);
  stageG(W1, ldW, col0,       0, sB[0] + 8192, tid);
  stageG(A,  ldA, row0,       0, sA[0],        tid);
  stageG(A,  ldA, row0 + 128, 0, sA[0] + 8192, tid);
  FENCE();
  if (NT > 1) {
    stageG(W0, ldW, col0,       64, sB[1],        tid);
    stageG(W1, ldW, col0,       64, sB[1] + 8192, tid);
    stageG(A,  ldA, row0,       64, sA[1],        tid);
    stageG(A,  ldA, row0 + 128, 64, sA[1] + 8192, tid);
    VMC(8);
  } else {
    VMC(0);
  }
  BARSYNC();

  for (int t = 0; t < NT; ++t) {
    const int b = t & 1;
    const u16* Ab = sA[b];
    const u16* Bb = sB[b];
    bf16x8 afL[4][2], afH[4][2], bf0[2][2], bf1[2][2];
    const int kN = (t + 2) * 64;

    readA4(afL, Ab, wm * 128 + lm, quad);
    readB2(bf0, Bb, wn * 32 + lm, quad);
    readB2(bf1, Bb + 8192, wn * 32 + lm, quad);
    readA4(afH, Ab, wm * 128 + 64 + lm, quad);

    mfmaQ<0, 0>(acc0, afL, bf0);
    mfmaQ<0, 0>(acc1, afL, bf1);

    BARSYNC();                            // both B regions of buf b free
    if (t + 2 < NT) {
      stageG(W0, ldW, col0, kN, (u16*)sB[b],        tid);
      stageG(W1, ldW, col0, kN, (u16*)sB[b] + 8192, tid);
    }
    mfmaQ<4, 0>(acc1, afH, bf1);

    BARSYNC();                            // A region of buf b free
    if (t + 2 < NT) {
      stageG(A, ldA, row0,       kN, (u16*)sA[b],        tid);
      stageG(A, ldA, row0 + 128, kN, (u16*)sA[b] + 8192, tid);
    }
    mfmaQ<4, 0>(acc0, afH, bf0);
    if (t + 2 < NT) { VMC(8); } else { VMC(0); }
    BARSYNC();
  }

#pragma unroll
  for (int mi = 0; mi < 8; ++mi) {
    const int rb = row0 + wm * 128 + mi * 16 + quad * 4;
#pragma unroll
    for (int ni = 0; ni < 2; ++ni) {
      const int cg = col0 + wn * 32 + ni * 16 + lm;
#pragma unroll
      for (int rr = 0; rr < 4; ++rr) {
        size_t idx = (size_t)(rb + rr) * N + cg;
        float v0 = acc0[mi][ni][rr];
        float v1 = acc1[mi][ni][rr];
        if constexpr (EPI == EPI2_XG) {
          out0[idx] = f2bf(v0);                 // xin raw
          out1[idx] = f2bf(sigm(v1));           // gate
        } else {
          out0[idx] = f2bf(v0 * sigm(v0) * v1); // m = silu(g) * u
        }
      }
    }
  }
}

// ---------------------------------------------------------------------------
// Chunked scan (unchanged).
__global__ void scan_phase1(const f16* __restrict__ z, const u16* __restrict__ xin,
                            float2* __restrict__ ch_h, float2* __restrict__ ch_p) {
  int gtid = blockIdx.x * 256 + threadIdx.x;
  int c = gtid >> 12;
  int pair = gtid & (NPAIR - 1);
  int b = pair >> 10;
  int d = (pair & 1023) * 2;
  size_t base = ((size_t)b * TLEN + (size_t)c * CHUNK) * DREC + d;
  float2 h = {0.f, 0.f}, P = {1.f, 1.f};
#pragma unroll 8
  for (int t = 0; t < CHUNK; ++t) {
    size_t i = base + (size_t)t * DREC;
    f16 z2[2]; *(uint32_t*)z2 = *(const uint32_t*)(z + i);
    u16 x2[2]; *(uint32_t*)x2 = *(const uint32_t*)(xin + i);
    float a0 = sigm((float)z2[0]), a1 = sigm((float)z2[1]);
    h.x = a0 * h.x + sqrtf(1.f - a0 * a0 + 1e-8f) * b2f(x2[0]);
    h.y = a1 * h.y + sqrtf(1.f - a1 * a1 + 1e-8f) * b2f(x2[1]);
    P.x *= a0; P.y *= a1;
  }
  ch_h[gtid] = h;
  ch_p[gtid] = P;
}

__global__ void scan_phase2(float2* __restrict__ ch_h, const float2* __restrict__ ch_p) {
  int pair = blockIdx.x * 256 + threadIdx.x;
  float2 H = {0.f, 0.f};
#pragma unroll
  for (int c = 0; c < NCH; ++c) {
    int i = c * NPAIR + pair;
    float2 he = ch_h[i];
    float2 P  = ch_p[i];
    ch_h[i] = H;
    H.x = he.x + P.x * H.x;
    H.y = he.y + P.y * H.y;
  }
}

__global__ void scan_phase3(const f16* __restrict__ z, const u16* __restrict__ xin,
                            u16* gate_y, const float2* __restrict__ ch_h) {
  int gtid = blockIdx.x * 256 + threadIdx.x;
  int c = gtid >> 12;
  int pair = gtid & (NPAIR - 1);
  int b = pair >> 10;
  int d = (pair & 1023) * 2;
  size_t base = ((size_t)b * TLEN + (size_t)c * CHUNK) * DREC + d;
  float2 h = ch_h[gtid];
#pragma unroll 8
  for (int t = 0; t < CHUNK; ++t) {
    size_t i = base + (size_t)t * DREC;
    f16 z2[2]; *(uint32_t*)z2 = *(const uint32_t*)(z + i);
    u16 x2[2]; *(uint32_t*)x2 = *(const uint32_t*)(xin + i);
    u16 g2[2]; *(uint32_t*)g2 = *(const uint32_t*)(gate_y + i);
    float a0 = sigm((float)z2[0]), a1 = sigm((float)z2[1]);
    h.x = a0 * h.x + sqrtf(1.f - a0 * a0 + 1e-8f) * b2f(x2[0]);
    h.y = a1 * h.y + sqrtf(1.f - a1 * a1 + 1e-8f) * b2f(x2[1]);
    u16 o2[2];
    o2[0] = f2bf(b2f(g2[0]) * h.x);
    o2[1] = f2bf(b2f(g2[1]) * h.y);
    *(uint32_t*)(gate_y + i) = *(uint32_t*)o2;
  }
}

// ---------------------------------------------------------------------------
extern "C" void kernel_launch(void* const* d_in, const int* in_sizes, int n_in,
                              void* d_out, int out_size, void* d_ws, size_t ws_size,
                              hipStream_t stream) {
  const float* x      = (const float*)d_in[0];
  const float* ln1    = (const float*)d_in[1];
  const float* ln2    = (const float*)d_in[2];
  const float* w_in   = (const float*)d_in[3];
  const float* w_gate = (const float*)d_in[4];
  const float* a_par  = (const float*)d_in[5];
  const float* w_a    = (const float*)d_in[6];
  const float* w_out  = (const float*)d_in[7];
  const float* w_mg   = (const float*)d_in[8];
  const float* w_mu   = (const float*)d_in[9];
  const float* w_md   = (const float*)d_in[10];
  float* out = (float*)d_out;
  char* ws = (char*)d_ws;

  const size_t MB = 1024ull * 1024ull;
  u16* wb_in  = (u16*)(ws + 0 * MB);
  u16* wb_gt  = (u16*)(ws + 4 * MB);
  u16* wb_a   = (u16*)(ws + 8 * MB);
  u16* wb_out = (u16*)(ws + 16 * MB);
  u16* wb_mg  = (u16*)(ws + 20 * MB);
  u16* wb_mu  = (u16*)(ws + 28 * MB);
  u16* wb_md  = (u16*)(ws + 36 * MB);
  u16* hbuf  = (u16*)(ws + 44 * MB);
  f16* zbuf  = (f16*)(ws + 44 * MB);
  u16* gateb = (u16*)(ws + 108 * MB);
  u16* mbuf  = (u16*)(ws + 108 * MB);
  float2* chh = (float2*)(ws + 0 * MB);
  float2* chp = (float2*)(ws + 2 * MB);
  u16* xinb = (u16*)d_out;

  // 1) all weights -> bf16
  f2b_all<<<22528, 256, 0, stream>>>(w_in, w_gate, w_a, w_out, w_mg, w_mu, w_md,
                                     wb_in, wb_gt, wb_a, wb_out, wb_mg, wb_mu, wb_md);

  // 2) h = rmsnorm(x, ln1)
  rmsnorm_kernel<<<BT, 256, 0, stream>>>(x, ln1, hbuf);

  // 3) fused: xin = h@w_in^T (raw -> d_out), gate = sigmoid(h@w_gate^T)
  gemm256d<EPI2_XG><<<dim3(BT / 256, DREC / 128), 512, 0, stream>>>(
      hbuf, wb_in, wb_gt, HID, DREC, HID, HID, xinb, gateb);

  // 4) z = a_param + xin@w_a^T (fp16 logits)
  gemm256<EPI_LOGIT><<<dim3(BT / 256, DREC / 256), 512, 0, stream>>>(
      xinb, wb_a, DREC, DREC, DREC, DREC, nullptr, zbuf, a_par);

  // 5) chunked scan; y = gate*h in place over gate
  scan_phase1<<<NCH * NPAIR / 256, 256, 0, stream>>>(zbuf, xinb, chh, chp);
  scan_phase2<<<NPAIR / 256, 256, 0, stream>>>(chh, chp);
  scan_phase3<<<NCH * NPAIR / 256, 256, 0, stream>>>(zbuf, xinb, gateb, chh);

  // 6) xr = x + y@w_out^T -> d_out (xin dead)
  gemm256<EPI_ADDF><<<dim3(BT / 256, HID / 256), 512, 0, stream>>>(
      gateb, wb_out, DREC, HID, DREC, DREC, out, nullptr, x);

  // 7) h2 = rmsnorm(xr, ln2)
  rmsnorm_kernel<<<BT, 256, 0, stream>>>(out, ln2, hbuf);

  // 8) MLP in two INTER halves; down-GEMM accumulates into d_out in place
  for (int half = 0; half < 2; ++half) {
    const u16* wmg_h = wb_mg + (size_t)half * 2048 * HID;
    const u16* wmu_h = wb_mu + (size_t)half * 2048 * HID;
    const u16* wmd_h = wb_md + (size_t)half * 2048;      // column slice, ldW=INTER
    gemm256d<EPI2_SM><<<dim3(BT / 256, 2048 / 128), 512, 0, stream>>>(
        hbuf, wmg_h, wmu_h, HID, 2048, HID, HID, mbuf, nullptr);
    gemm256<EPI_ADDF><<<dim3(BT / 256, HID / 256), 512, 0, stream>>>(
        mbuf, wmd_h, 2048, HID, 2048, INTER, out, nullptr, out);
  }
}

// Round 5
// 1146.938 us; speedup vs baseline: 1.0830x; 1.0390x over previous
//
#include <hip/hip_runtime.h>
#include <cstdint>
#include <cmath>

// ---------------------------------------------------------------------------
// HawkBlock on MI355X (gfx950). Round 9 (= R8 resubmitted; container infra
// failure last round, no counters).
// R5-R7 post-mortem: all 256^2 1-block/CU schedules stuck at ~835 TF (MfmaUtil
// 34-35%) — losing the m114 inter-block latency hiding that the 128^2
// 3-block/CU structure gets for free (R4: 1406 cyc/K-step vs 1388 serial
// read+MFMA chain = stalls fully hidden). Guide tile-space data agrees
// (128^2=912 > 128x256=823 > 256^2=792). R8/R9: revert to the R4 kernels
// (harness-verified 1166 us) + L2/XCD-aware block remap on all GEMMs:
// row-major rid + bijective XCD chunking so each XCD's consecutive blocks
// share an A row-panel (L2-resident) and W panels stay L3-resident.
// Evidence: z-GEMM FETCH 252 MB vs ideal 72 MB (A leaked ~3x from HBM).
// Scan / rmsnorm / f2b unchanged.
// ---------------------------------------------------------------------------

typedef unsigned short u16;
typedef _Float16 f16;
typedef __bf16 bf16x8 __attribute__((ext_vector_type(8)));
typedef float  f32x4  __attribute__((ext_vector_type(4)));

#define BM 128
#define BN 128
#define BK 64

#define HID   1024
#define DREC  2048
#define INTER 4096
#define BT    16384   // B*T rows
#define TLEN  4096
#define NCHAN 8192    // B * DREC
#define CHUNK 64
#define NCH   64      // TLEN / CHUNK
#define NPAIR 4096    // NCHAN/2 channel pairs

__device__ __forceinline__ float b2f(u16 u) {
  union { unsigned int i; float f; } v; v.i = ((unsigned int)u) << 16; return v.f;
}
__device__ __forceinline__ u16 f2bf(float f) {  // RNE
  unsigned int u = __builtin_bit_cast(unsigned int, f);
  u += 0x7FFFu + ((u >> 16) & 1u);
  return (u16)(u >> 16);
}
__device__ __forceinline__ float sigm(float x) { return 1.f / (1.f + expf(-x)); }

typedef __attribute__((address_space(1))) void as1_void;
typedef __attribute__((address_space(3))) void as3_void;
__device__ __forceinline__ void async16(const void* g, void* l) {
  __builtin_amdgcn_global_load_lds((as1_void*)g, (as3_void*)l, 16, 0, 0);
}

// XCD-aware remap (T1): hardware round-robins linear block id across 8 XCDs;
// give XCD k the contiguous row-major chunk [k*nwg/8,(k+1)*nwg/8) so its
// consecutive blocks share one A row-panel (L2 hit) while sweeping cols.
// Bijective because every GEMM grid here has nwg % 8 == 0 (gx = 128).
__device__ __forceinline__ void xcd_remap(int& bx, int& by) {
  const int gx = gridDim.x, gy = gridDim.y;
  const int nwg = gx * gy;
  const int lid = blockIdx.x + gx * blockIdx.y;
  const int rid = (lid & 7) * (nwg >> 3) + (lid >> 3);   // XCD-contiguous
  bx = rid / gy;                                         // row panel
  by = rid - bx * gy;                                    // col panel
}

// ---------------------------------------------------------------------------
// All 7 weight conversions in ONE kernel. Segment boundaries are compile-time
// block counts (all multiples of 256 float4s -> no intra-block straddle).
__global__ void f2b_all(const float* s0, const float* s1, const float* s2,
                        const float* s3, const float* s4, const float* s5,
                        const float* s6,
                        u16* d0, u16* d1, u16* d2, u16* d3, u16* d4, u16* d5,
                        u16* d6) {
  // block counts: 2048,2048,4096,2048,4096,4096,4096 (total 22528)
  int blk = blockIdx.x;
  const float* src; u16* dst; int rel;
  if      (blk < 2048)  { src = s0; dst = d0; rel = blk; }
  else if (blk < 4096)  { src = s1; dst = d1; rel = blk - 2048; }
  else if (blk < 8192)  { src = s2; dst = d2; rel = blk - 4096; }
  else if (blk < 10240) { src = s3; dst = d3; rel = blk - 8192; }
  else if (blk < 14336) { src = s4; dst = d4; rel = blk - 10240; }
  else if (blk < 18432) { src = s5; dst = d5; rel = blk - 14336; }
  else                  { src = s6; dst = d6; rel = blk - 18432; }
  int i = rel * 256 + threadIdx.x;
  float4 v = ((const float4*)src)[i];
  ushort4 o;
  o.x = f2bf(v.x); o.y = f2bf(v.y); o.z = f2bf(v.z); o.w = f2bf(v.w);
  ((ushort4*)dst)[i] = o;
}

// rmsnorm over rows of 1024 fp32, bf16 out. One 256-thread block per row.
__global__ void rmsnorm_kernel(const float* __restrict__ x, const float* __restrict__ w,
                               u16* __restrict__ out) {
  const int row = blockIdx.x;
  const int tid = threadIdx.x;
  float4 v = ((const float4*)(x + (size_t)row * HID))[tid];
  float ss = v.x * v.x + v.y * v.y + v.z * v.z + v.w * v.w;
#pragma unroll
  for (int o = 32; o > 0; o >>= 1) ss += __shfl_down(ss, o);
  __shared__ float red[4];
  const int lane = tid & 63, wv = tid >> 6;
  if (lane == 0) red[wv] = ss;
  __syncthreads();
  float tot = red[0] + red[1] + red[2] + red[3];
  float sc = rsqrtf(tot * (1.f / (float)HID) + 1e-6f);
  float4 wv4 = ((const float4*)w)[tid];
  ushort4 o;
  o.x = f2bf(v.x * sc * wv4.x); o.y = f2bf(v.y * sc * wv4.y);
  o.z = f2bf(v.z * sc * wv4.z); o.w = f2bf(v.w * sc * wv4.w);
  ((ushort4*)(out + (size_t)row * HID))[tid] = o;
}

// ---------------------------------------------------------------------------
// Single-B GEMM: C[M,N] = A[M,K] @ W[N,K]^T (rows strided ldA/ldW), fp32 acc.
enum { EPI_LOGIT = 0, EPI_ADDF = 1 };

template <int EPI>
__global__ __launch_bounds__(256, 3)
void gemm1(const u16* __restrict__ A, const u16* __restrict__ W,
           int K, int N, int ldA, int ldW,
           float* outf, f16* outz, const float* auxf) {
  __shared__ alignas(16) u16 sA[BM * BK];
  __shared__ alignas(16) u16 sB[BN * BK];

  const int tid  = threadIdx.x;
  const int lane = tid & 63;
  const int wv   = tid >> 6;
  const int wm   = wv & 1;
  const int wn   = wv >> 1;
  const int lm   = lane & 15;
  const int quad = lane >> 4;

  int bx, by;
  xcd_remap(bx, by);
  const int row0 = bx * BM;
  const int col0 = by * BN;

  f32x4 acc[4][4];
#pragma unroll
  for (int i = 0; i < 4; ++i)
#pragma unroll
    for (int j = 0; j < 4; ++j) acc[i][j] = (f32x4)0.f;

  for (int k0 = 0; k0 < K; k0 += BK) {
#pragma unroll
    for (int i = 0; i < 4; ++i) {
      int p = i * 256 + tid;
      int r = p >> 3;
      int sg = (p & 7) ^ (r & 7);
      async16(A + (size_t)(row0 + r) * ldA + (k0 + sg * 8), (char*)sA + p * 16);
    }
#pragma unroll
    for (int i = 0; i < 4; ++i) {
      int p = i * 256 + tid;
      int r = p >> 3;
      int sg = (p & 7) ^ (r & 7);
      async16(W + (size_t)(col0 + r) * ldW + (k0 + sg * 8), (char*)sB + p * 16);
    }
    __syncthreads();

#pragma unroll
    for (int h = 0; h < 2; ++h) {
      bf16x8 af[4], bf[4];
#pragma unroll
      for (int mi = 0; mi < 4; ++mi) {
        int r = wm * 64 + mi * 16 + lm;
        af[mi] = ((const bf16x8*)sA)[r * 8 + ((h * 4 + quad) ^ (r & 7))];
      }
#pragma unroll
      for (int ni = 0; ni < 4; ++ni) {
        int c = wn * 64 + ni * 16 + lm;
        bf[ni] = ((const bf16x8*)sB)[c * 8 + ((h * 4 + quad) ^ (c & 7))];
      }
#pragma unroll
      for (int mi = 0; mi < 4; ++mi)
#pragma unroll
        for (int ni = 0; ni < 4; ++ni)
          acc[mi][ni] = __builtin_amdgcn_mfma_f32_16x16x32_bf16(af[mi], bf[ni], acc[mi][ni], 0, 0, 0);
    }
    __syncthreads();
  }

  // C/D layout: col = lane&15, row = quad*4 + reg  (m89/m91-verified)
#pragma unroll
  for (int mi = 0; mi < 4; ++mi) {
    const int rbase = row0 + wm * 64 + mi * 16 + quad * 4;
#pragma unroll
    for (int ni = 0; ni < 4; ++ni) {
      const int cg = col0 + wn * 64 + ni * 16 + lm;
      f32x4 v = acc[mi][ni];
#pragma unroll
      for (int rr = 0; rr < 4; ++rr) {
        size_t idx = (size_t)(rbase + rr) * N + cg;
        float t = v[rr];
        if constexpr (EPI == EPI_LOGIT) {
          outz[idx] = (f16)(t + auxf[cg]);      // pre-sigmoid logit, fp16
        } else {
          outf[idx] = t + auxf[idx];            // residual add; auxf may == outf
        }
      }
    }
  }
}

// ---------------------------------------------------------------------------
// Dual-B GEMM: per-B tile 128x64, wave tile 64x32 per matrix, acc 64 regs,
// LDS 32KB, lb(256,3).
enum { EPI2_XG = 0, EPI2_SM = 1 };

template <int EPI>
__global__ __launch_bounds__(256, 3)
void gemm2(const u16* __restrict__ A, const u16* __restrict__ W0,
           const u16* __restrict__ W1,
           int K, int N, int ldA, int ldW,
           u16* out0, u16* out1) {
  __shared__ alignas(16) u16 sA[BM * BK];     // 128 x 64
  __shared__ alignas(16) u16 sB0[64 * BK];    // 64 x 64
  __shared__ alignas(16) u16 sB1[64 * BK];

  const int tid  = threadIdx.x;
  const int lane = tid & 63;
  const int wv   = tid >> 6;
  const int wm   = wv & 1;   // row half (64 rows)
  const int wn   = wv >> 1;  // col half (32 cols per matrix)
  const int lm   = lane & 15;
  const int quad = lane >> 4;

  int bx, by;
  xcd_remap(bx, by);
  const int row0 = bx * BM;
  const int col0 = by * 64;

  f32x4 acc0[4][2], acc1[4][2];
#pragma unroll
  for (int i = 0; i < 4; ++i)
#pragma unroll
    for (int j = 0; j < 2; ++j) { acc0[i][j] = (f32x4)0.f; acc1[i][j] = (f32x4)0.f; }

  for (int k0 = 0; k0 < K; k0 += BK) {
#pragma unroll
    for (int i = 0; i < 4; ++i) {             // A: 1024 segments of 16B
      int p = i * 256 + tid;
      int r = p >> 3;
      int sg = (p & 7) ^ (r & 7);
      async16(A + (size_t)(row0 + r) * ldA + (k0 + sg * 8), (char*)sA + p * 16);
    }
#pragma unroll
    for (int i = 0; i < 2; ++i) {             // B0/B1: 512 segments each
      int p = i * 256 + tid;
      int r = p >> 3;
      int sg = (p & 7) ^ (r & 7);
      size_t go = (size_t)(col0 + r) * ldW + (k0 + sg * 8);
      async16(W0 + go, (char*)sB0 + p * 16);
      async16(W1 + go, (char*)sB1 + p * 16);
    }
    __syncthreads();

#pragma unroll
    for (int h = 0; h < 2; ++h) {
      bf16x8 af[4], b0[2], b1[2];
#pragma unroll
      for (int mi = 0; mi < 4; ++mi) {
        int r = wm * 64 + mi * 16 + lm;
        af[mi] = ((const bf16x8*)sA)[r * 8 + ((h * 4 + quad) ^ (r & 7))];
      }
#pragma unroll
      for (int ni = 0; ni < 2; ++ni) {
        int c = wn * 32 + ni * 16 + lm;
        int o = c * 8 + ((h * 4 + quad) ^ (c & 7));
        b0[ni] = ((const bf16x8*)sB0)[o];
        b1[ni] = ((const bf16x8*)sB1)[o];
      }
#pragma unroll
      for (int mi = 0; mi < 4; ++mi)
#pragma unroll
        for (int ni = 0; ni < 2; ++ni) {
          acc0[mi][ni] = __builtin_amdgcn_mfma_f32_16x16x32_bf16(af[mi], b0[ni], acc0[mi][ni], 0, 0, 0);
          acc1[mi][ni] = __builtin_amdgcn_mfma_f32_16x16x32_bf16(af[mi], b1[ni], acc1[mi][ni], 0, 0, 0);
        }
    }
    __syncthreads();
  }

#pragma unroll
  for (int mi = 0; mi < 4; ++mi) {
    const int rbase = row0 + wm * 64 + mi * 16 + quad * 4;
#pragma unroll
    for (int ni = 0; ni < 2; ++ni) {
      const int cg = col0 + wn * 32 + ni * 16 + lm;
#pragma unroll
      for (int rr = 0; rr < 4; ++rr) {
        size_t idx = (size_t)(rbase + rr) * N + cg;
        float v0 = acc0[mi][ni][rr];
        float v1 = acc1[mi][ni][rr];
        if constexpr (EPI == EPI2_XG) {
          out0[idx] = f2bf(v0);                 // xin raw
          out1[idx] = f2bf(sigm(v1));           // gate
        } else {
          out0[idx] = f2bf(v0 * sigm(v0) * v1); // m = silu(g) * u
        }
      }
    }
  }
}

// ---------------------------------------------------------------------------
// Chunked scan, 2 channels/thread, 64 chunks of 64 steps -> 1024 blocks.
// a_t = sigmoid(z_t); h_t = a_t h_{t-1} + sqrt(1-a_t^2+1e-8) x_t
__global__ void scan_phase1(const f16* __restrict__ z, const u16* __restrict__ xin,
                            float2* __restrict__ ch_h, float2* __restrict__ ch_p) {
  int gtid = blockIdx.x * 256 + threadIdx.x;   // 64 chunks x 4096 pairs
  int c = gtid >> 12;
  int pair = gtid & (NPAIR - 1);
  int b = pair >> 10;                          // DREC/2 = 1024 pairs per batch
  int d = (pair & 1023) * 2;
  size_t base = ((size_t)b * TLEN + (size_t)c * CHUNK) * DREC + d;
  float2 h = {0.f, 0.f}, P = {1.f, 1.f};
#pragma unroll 8
  for (int t = 0; t < CHUNK; ++t) {
    size_t i = base + (size_t)t * DREC;
    f16 z2[2]; *(uint32_t*)z2 = *(const uint32_t*)(z + i);
    u16 x2[2]; *(uint32_t*)x2 = *(const uint32_t*)(xin + i);
    float a0 = sigm((float)z2[0]), a1 = sigm((float)z2[1]);
    h.x = a0 * h.x + sqrtf(1.f - a0 * a0 + 1e-8f) * b2f(x2[0]);
    h.y = a1 * h.y + sqrtf(1.f - a1 * a1 + 1e-8f) * b2f(x2[1]);
    P.x *= a0; P.y *= a1;
  }
  ch_h[gtid] = h;
  ch_p[gtid] = P;
}

__global__ void scan_phase2(float2* __restrict__ ch_h, const float2* __restrict__ ch_p) {
  int pair = blockIdx.x * 256 + threadIdx.x;   // 4096 pairs
  float2 H = {0.f, 0.f};
#pragma unroll
  for (int c = 0; c < NCH; ++c) {
    int i = c * NPAIR + pair;
    float2 he = ch_h[i];
    float2 P  = ch_p[i];
    ch_h[i] = H;          // carry-in for this chunk
    H.x = he.x + P.x * H.x;
    H.y = he.y + P.y * H.y;
  }
}

// Phase 3: rescan with carry-in; y = gate*h written IN PLACE over gate.
__global__ void scan_phase3(const f16* __restrict__ z, const u16* __restrict__ xin,
                            u16* gate_y, const float2* __restrict__ ch_h) {
  int gtid = blockIdx.x * 256 + threadIdx.x;
  int c = gtid >> 12;
  int pair = gtid & (NPAIR - 1);
  int b = pair >> 10;
  int d = (pair & 1023) * 2;
  size_t base = ((size_t)b * TLEN + (size_t)c * CHUNK) * DREC + d;
  float2 h = ch_h[gtid];
#pragma unroll 8
  for (int t = 0; t < CHUNK; ++t) {
    size_t i = base + (size_t)t * DREC;
    f16 z2[2]; *(uint32_t*)z2 = *(const uint32_t*)(z + i);
    u16 x2[2]; *(uint32_t*)x2 = *(const uint32_t*)(xin + i);
    u16 g2[2]; *(uint32_t*)g2 = *(const uint32_t*)(gate_y + i);
    float a0 = sigm((float)z2[0]), a1 = sigm((float)z2[1]);
    h.x = a0 * h.x + sqrtf(1.f - a0 * a0 + 1e-8f) * b2f(x2[0]);
    h.y = a1 * h.y + sqrtf(1.f - a1 * a1 + 1e-8f) * b2f(x2[1]);
    u16 o2[2];
    o2[0] = f2bf(b2f(g2[0]) * h.x);
    o2[1] = f2bf(b2f(g2[1]) * h.y);
    *(uint32_t*)(gate_y + i) = *(uint32_t*)o2;
  }
}

// ---------------------------------------------------------------------------
extern "C" void kernel_launch(void* const* d_in, const int* in_sizes, int n_in,
                              void* d_out, int out_size, void* d_ws, size_t ws_size,
                              hipStream_t stream) {
  const float* x      = (const float*)d_in[0];
  const float* ln1    = (const float*)d_in[1];
  const float* ln2    = (const float*)d_in[2];
  const float* w_in   = (const float*)d_in[3];
  const float* w_gate = (const float*)d_in[4];
  const float* a_par  = (const float*)d_in[5];
  const float* w_a    = (const float*)d_in[6];
  const float* w_out  = (const float*)d_in[7];
  const float* w_mg   = (const float*)d_in[8];
  const float* w_mu   = (const float*)d_in[9];
  const float* w_md   = (const float*)d_in[10];
  float* out = (float*)d_out;
  char* ws = (char*)d_ws;

  const size_t MB = 1024ull * 1024ull;
  // bf16 weights: 0..44 MB
  u16* wb_in  = (u16*)(ws + 0 * MB);    // 4 MB  (dead after step 3)
  u16* wb_gt  = (u16*)(ws + 4 * MB);    // 4 MB  (dead after step 3)
  u16* wb_a   = (u16*)(ws + 8 * MB);    // 8 MB
  u16* wb_out = (u16*)(ws + 16 * MB);   // 4 MB
  u16* wb_mg  = (u16*)(ws + 20 * MB);   // 8 MB
  u16* wb_mu  = (u16*)(ws + 28 * MB);   // 8 MB
  u16* wb_md  = (u16*)(ws + 36 * MB);   // 8 MB
  // activations (time-multiplexed)
  u16* hbuf  = (u16*)(ws + 44 * MB);    // 32 MB: h, later h2
  f16* zbuf  = (f16*)(ws + 44 * MB);    // 64 MB: a-logits (over dead h)
  u16* gateb = (u16*)(ws + 108 * MB);   // 64 MB: gate -> y -> dead
  u16* mbuf  = (u16*)(ws + 108 * MB);   // 64 MB: mlp half (after y dead)
  // chunk summaries (2 MB each) overlay wb_in/wb_gt (dead once scan starts)
  float2* chh = (float2*)(ws + 0 * MB);
  float2* chp = (float2*)(ws + 2 * MB);
  u16* xinb = (u16*)d_out;              // d_out as scratch: xin, then xr
  // high-water: 173 MB of ws

  // 1) all weights -> bf16 in one launch
  f2b_all<<<22528, 256, 0, stream>>>(w_in, w_gate, w_a, w_out, w_mg, w_mu, w_md,
                                     wb_in, wb_gt, wb_a, wb_out, wb_mg, wb_mu, wb_md);

  // 2) h = rmsnorm(x, ln1)
  rmsnorm_kernel<<<BT, 256, 0, stream>>>(x, ln1, hbuf);

  // 3) fused: xin = h@w_in^T (raw, -> d_out), gate = sigmoid(h@w_gate^T)
  gemm2<EPI2_XG><<<dim3(BT / BM, DREC / 64), 256, 0, stream>>>(
      hbuf, wb_in, wb_gt, HID, DREC, HID, HID, xinb, gateb);

  // 4) z = a_param + xin@w_a^T  (fp16 logits)
  gemm1<EPI_LOGIT><<<dim3(BT / BM, DREC / BN), 256, 0, stream>>>(
      xinb, wb_a, DREC, DREC, DREC, DREC, nullptr, zbuf, a_par);

  // 5) chunked scan; y = gate*h in place over gate
  scan_phase1<<<NCH * NPAIR / 256, 256, 0, stream>>>(zbuf, xinb, chh, chp);
  scan_phase2<<<NPAIR / 256, 256, 0, stream>>>(chh, chp);
  scan_phase3<<<NCH * NPAIR / 256, 256, 0, stream>>>(zbuf, xinb, gateb, chh);

  // 6) xr = x + y@w_out^T  -> d_out (xin dead)
  gemm1<EPI_ADDF><<<dim3(BT / BM, HID / BN), 256, 0, stream>>>(
      gateb, wb_out, DREC, HID, DREC, DREC, out, nullptr, x);

  // 7) h2 = rmsnorm(xr, ln2)
  rmsnorm_kernel<<<BT, 256, 0, stream>>>(out, ln2, hbuf);

  // 8) MLP in two INTER halves; down-GEMM accumulates into d_out in place
  for (int half = 0; half < 2; ++half) {
    const u16* wmg_h = wb_mg + (size_t)half * 2048 * HID;
    const u16* wmu_h = wb_mu + (size_t)half * 2048 * HID;
    const u16* wmd_h = wb_md + (size_t)half * 2048;      // column slice, ldW=INTER
    gemm2<EPI2_SM><<<dim3(BT / BM, 2048 / 64), 256, 0, stream>>>(
        hbuf, wmg_h, wmu_h, HID, 2048, HID, HID, mbuf, nullptr);
    gemm1<EPI_ADDF><<<dim3(BT / BM, HID / BN), 256, 0, stream>>>(
        mbuf, wmd_h, 2048, HID, 2048, INTER, out, nullptr, out);
  }
}

// Round 6
// 1122.215 us; speedup vs baseline: 1.1069x; 1.0220x over previous
//
#include <hip/hip_runtime.h>
#include <cstdint>
#include <cmath>

// ---------------------------------------------------------------------------
// HawkBlock on MI355X (gfx950). Round 10.
// R9 post-mortem (1147 us, best): XCD row-remap helped gemm1 (z-GEMM A-panel
// reuse; total -75 us ex-gemm2) but HURT gemm2 by ~6% (150->159 us, FETCH
// 433 MB): gemm2's default dispatch already keeps W col-panels (512 KB)
// L2-resident across 128 consecutive blocks; row-remap made the per-XCD W
// working set 8 MB > 4 MB L2 -> W streamed from L3 every row-sweep.
// R10: (1) revert remap in gemm2 only (identity mapping); keep remap in
// gemm1. (2) __launch_bounds__(256,4) on both GEMMs (VGPR 60-64, LDS 32KB
// permit 4-5 blocks/CU; measured occupancy ~3.07 blocks — test if lb-capped).
// Scan / rmsnorm / f2b unchanged.
// ---------------------------------------------------------------------------

typedef unsigned short u16;
typedef _Float16 f16;
typedef __bf16 bf16x8 __attribute__((ext_vector_type(8)));
typedef float  f32x4  __attribute__((ext_vector_type(4)));

#define BM 128
#define BN 128
#define BK 64

#define HID   1024
#define DREC  2048
#define INTER 4096
#define BT    16384   // B*T rows
#define TLEN  4096
#define NCHAN 8192    // B * DREC
#define CHUNK 64
#define NCH   64      // TLEN / CHUNK
#define NPAIR 4096    // NCHAN/2 channel pairs

__device__ __forceinline__ float b2f(u16 u) {
  union { unsigned int i; float f; } v; v.i = ((unsigned int)u) << 16; return v.f;
}
__device__ __forceinline__ u16 f2bf(float f) {  // RNE
  unsigned int u = __builtin_bit_cast(unsigned int, f);
  u += 0x7FFFu + ((u >> 16) & 1u);
  return (u16)(u >> 16);
}
__device__ __forceinline__ float sigm(float x) { return 1.f / (1.f + expf(-x)); }

typedef __attribute__((address_space(1))) void as1_void;
typedef __attribute__((address_space(3))) void as3_void;
__device__ __forceinline__ void async16(const void* g, void* l) {
  __builtin_amdgcn_global_load_lds((as1_void*)g, (as3_void*)l, 16, 0, 0);
}

// XCD-aware remap (T1), used by gemm1 only: give XCD k the contiguous
// row-major chunk [k*nwg/8,(k+1)*nwg/8) so its consecutive blocks share one
// A row-panel (L2 hit) while sweeping cols. Bijective (nwg % 8 == 0: gx=128).
__device__ __forceinline__ void xcd_remap(int& bx, int& by) {
  const int gx = gridDim.x, gy = gridDim.y;
  const int nwg = gx * gy;
  const int lid = blockIdx.x + gx * blockIdx.y;
  const int rid = (lid & 7) * (nwg >> 3) + (lid >> 3);   // XCD-contiguous
  bx = rid / gy;                                         // row panel
  by = rid - bx * gy;                                    // col panel
}

// ---------------------------------------------------------------------------
// All 7 weight conversions in ONE kernel. Segment boundaries are compile-time
// block counts (all multiples of 256 float4s -> no intra-block straddle).
__global__ void f2b_all(const float* s0, const float* s1, const float* s2,
                        const float* s3, const float* s4, const float* s5,
                        const float* s6,
                        u16* d0, u16* d1, u16* d2, u16* d3, u16* d4, u16* d5,
                        u16* d6) {
  // block counts: 2048,2048,4096,2048,4096,4096,4096 (total 22528)
  int blk = blockIdx.x;
  const float* src; u16* dst; int rel;
  if      (blk < 2048)  { src = s0; dst = d0; rel = blk; }
  else if (blk < 4096)  { src = s1; dst = d1; rel = blk - 2048; }
  else if (blk < 8192)  { src = s2; dst = d2; rel = blk - 4096; }
  else if (blk < 10240) { src = s3; dst = d3; rel = blk - 8192; }
  else if (blk < 14336) { src = s4; dst = d4; rel = blk - 10240; }
  else if (blk < 18432) { src = s5; dst = d5; rel = blk - 14336; }
  else                  { src = s6; dst = d6; rel = blk - 18432; }
  int i = rel * 256 + threadIdx.x;
  float4 v = ((const float4*)src)[i];
  ushort4 o;
  o.x = f2bf(v.x); o.y = f2bf(v.y); o.z = f2bf(v.z); o.w = f2bf(v.w);
  ((ushort4*)dst)[i] = o;
}

// rmsnorm over rows of 1024 fp32, bf16 out. One 256-thread block per row.
__global__ void rmsnorm_kernel(const float* __restrict__ x, const float* __restrict__ w,
                               u16* __restrict__ out) {
  const int row = blockIdx.x;
  const int tid = threadIdx.x;
  float4 v = ((const float4*)(x + (size_t)row * HID))[tid];
  float ss = v.x * v.x + v.y * v.y + v.z * v.z + v.w * v.w;
#pragma unroll
  for (int o = 32; o > 0; o >>= 1) ss += __shfl_down(ss, o);
  __shared__ float red[4];
  const int lane = tid & 63, wv = tid >> 6;
  if (lane == 0) red[wv] = ss;
  __syncthreads();
  float tot = red[0] + red[1] + red[2] + red[3];
  float sc = rsqrtf(tot * (1.f / (float)HID) + 1e-6f);
  float4 wv4 = ((const float4*)w)[tid];
  ushort4 o;
  o.x = f2bf(v.x * sc * wv4.x); o.y = f2bf(v.y * sc * wv4.y);
  o.z = f2bf(v.z * sc * wv4.z); o.w = f2bf(v.w * sc * wv4.w);
  ((ushort4*)(out + (size_t)row * HID))[tid] = o;
}

// ---------------------------------------------------------------------------
// Single-B GEMM: C[M,N] = A[M,K] @ W[N,K]^T (rows strided ldA/ldW), fp32 acc.
// Uses xcd_remap (A-panel L2 residency; helped z-GEMM: FETCH 252 MB -> A-once).
enum { EPI_LOGIT = 0, EPI_ADDF = 1 };

template <int EPI>
__global__ __launch_bounds__(256, 4)
void gemm1(const u16* __restrict__ A, const u16* __restrict__ W,
           int K, int N, int ldA, int ldW,
           float* outf, f16* outz, const float* auxf) {
  __shared__ alignas(16) u16 sA[BM * BK];
  __shared__ alignas(16) u16 sB[BN * BK];

  const int tid  = threadIdx.x;
  const int lane = tid & 63;
  const int wv   = tid >> 6;
  const int wm   = wv & 1;
  const int wn   = wv >> 1;
  const int lm   = lane & 15;
  const int quad = lane >> 4;

  int bx, by;
  xcd_remap(bx, by);
  const int row0 = bx * BM;
  const int col0 = by * BN;

  f32x4 acc[4][4];
#pragma unroll
  for (int i = 0; i < 4; ++i)
#pragma unroll
    for (int j = 0; j < 4; ++j) acc[i][j] = (f32x4)0.f;

  for (int k0 = 0; k0 < K; k0 += BK) {
#pragma unroll
    for (int i = 0; i < 4; ++i) {
      int p = i * 256 + tid;
      int r = p >> 3;
      int sg = (p & 7) ^ (r & 7);
      async16(A + (size_t)(row0 + r) * ldA + (k0 + sg * 8), (char*)sA + p * 16);
    }
#pragma unroll
    for (int i = 0; i < 4; ++i) {
      int p = i * 256 + tid;
      int r = p >> 3;
      int sg = (p & 7) ^ (r & 7);
      async16(W + (size_t)(col0 + r) * ldW + (k0 + sg * 8), (char*)sB + p * 16);
    }
    __syncthreads();

#pragma unroll
    for (int h = 0; h < 2; ++h) {
      bf16x8 af[4], bf[4];
#pragma unroll
      for (int mi = 0; mi < 4; ++mi) {
        int r = wm * 64 + mi * 16 + lm;
        af[mi] = ((const bf16x8*)sA)[r * 8 + ((h * 4 + quad) ^ (r & 7))];
      }
#pragma unroll
      for (int ni = 0; ni < 4; ++ni) {
        int c = wn * 64 + ni * 16 + lm;
        bf[ni] = ((const bf16x8*)sB)[c * 8 + ((h * 4 + quad) ^ (c & 7))];
      }
#pragma unroll
      for (int mi = 0; mi < 4; ++mi)
#pragma unroll
        for (int ni = 0; ni < 4; ++ni)
          acc[mi][ni] = __builtin_amdgcn_mfma_f32_16x16x32_bf16(af[mi], bf[ni], acc[mi][ni], 0, 0, 0);
    }
    __syncthreads();
  }

  // C/D layout: col = lane&15, row = quad*4 + reg  (m89/m91-verified)
#pragma unroll
  for (int mi = 0; mi < 4; ++mi) {
    const int rbase = row0 + wm * 64 + mi * 16 + quad * 4;
#pragma unroll
    for (int ni = 0; ni < 4; ++ni) {
      const int cg = col0 + wn * 64 + ni * 16 + lm;
      f32x4 v = acc[mi][ni];
#pragma unroll
      for (int rr = 0; rr < 4; ++rr) {
        size_t idx = (size_t)(rbase + rr) * N + cg;
        float t = v[rr];
        if constexpr (EPI == EPI_LOGIT) {
          outz[idx] = (f16)(t + auxf[cg]);      // pre-sigmoid logit, fp16
        } else {
          outf[idx] = t + auxf[idx];            // residual add; auxf may == outf
        }
      }
    }
  }
}

// ---------------------------------------------------------------------------
// Dual-B GEMM: per-B tile 128x64, wave tile 64x32 per matrix, acc 64 regs,
// LDS 32KB. NO remap: default dispatch (x-fastest, XCD round-robin) keeps
// each W col-panel L2-resident across 128 consecutive blocks — measured
// better than row-remap (R4 <=149 us vs R9 159 us, FETCH 433 MB).
enum { EPI2_XG = 0, EPI2_SM = 1 };

template <int EPI>
__global__ __launch_bounds__(256, 4)
void gemm2(const u16* __restrict__ A, const u16* __restrict__ W0,
           const u16* __restrict__ W1,
           int K, int N, int ldA, int ldW,
           u16* out0, u16* out1) {
  __shared__ alignas(16) u16 sA[BM * BK];     // 128 x 64
  __shared__ alignas(16) u16 sB0[64 * BK];    // 64 x 64
  __shared__ alignas(16) u16 sB1[64 * BK];

  const int tid  = threadIdx.x;
  const int lane = tid & 63;
  const int wv   = tid >> 6;
  const int wm   = wv & 1;   // row half (64 rows)
  const int wn   = wv >> 1;  // col half (32 cols per matrix)
  const int lm   = lane & 15;
  const int quad = lane >> 4;

  const int row0 = blockIdx.x * BM;
  const int col0 = blockIdx.y * 64;

  f32x4 acc0[4][2], acc1[4][2];
#pragma unroll
  for (int i = 0; i < 4; ++i)
#pragma unroll
    for (int j = 0; j < 2; ++j) { acc0[i][j] = (f32x4)0.f; acc1[i][j] = (f32x4)0.f; }

  for (int k0 = 0; k0 < K; k0 += BK) {
#pragma unroll
    for (int i = 0; i < 4; ++i) {             // A: 1024 segments of 16B
      int p = i * 256 + tid;
      int r = p >> 3;
      int sg = (p & 7) ^ (r & 7);
      async16(A + (size_t)(row0 + r) * ldA + (k0 + sg * 8), (char*)sA + p * 16);
    }
#pragma unroll
    for (int i = 0; i < 2; ++i) {             // B0/B1: 512 segments each
      int p = i * 256 + tid;
      int r = p >> 3;
      int sg = (p & 7) ^ (r & 7);
      size_t go = (size_t)(col0 + r) * ldW + (k0 + sg * 8);
      async16(W0 + go, (char*)sB0 + p * 16);
      async16(W1 + go, (char*)sB1 + p * 16);
    }
    __syncthreads();

#pragma unroll
    for (int h = 0; h < 2; ++h) {
      bf16x8 af[4], b0[2], b1[2];
#pragma unroll
      for (int mi = 0; mi < 4; ++mi) {
        int r = wm * 64 + mi * 16 + lm;
        af[mi] = ((const bf16x8*)sA)[r * 8 + ((h * 4 + quad) ^ (r & 7))];
      }
#pragma unroll
      for (int ni = 0; ni < 2; ++ni) {
        int c = wn * 32 + ni * 16 + lm;
        int o = c * 8 + ((h * 4 + quad) ^ (c & 7));
        b0[ni] = ((const bf16x8*)sB0)[o];
        b1[ni] = ((const bf16x8*)sB1)[o];
      }
#pragma unroll
      for (int mi = 0; mi < 4; ++mi)
#pragma unroll
        for (int ni = 0; ni < 2; ++ni) {
          acc0[mi][ni] = __builtin_amdgcn_mfma_f32_16x16x32_bf16(af[mi], b0[ni], acc0[mi][ni], 0, 0, 0);
          acc1[mi][ni] = __builtin_amdgcn_mfma_f32_16x16x32_bf16(af[mi], b1[ni], acc1[mi][ni], 0, 0, 0);
        }
    }
    __syncthreads();
  }

#pragma unroll
  for (int mi = 0; mi < 4; ++mi) {
    const int rbase = row0 + wm * 64 + mi * 16 + quad * 4;
#pragma unroll
    for (int ni = 0; ni < 2; ++ni) {
      const int cg = col0 + wn * 32 + ni * 16 + lm;
#pragma unroll
      for (int rr = 0; rr < 4; ++rr) {
        size_t idx = (size_t)(rbase + rr) * N + cg;
        float v0 = acc0[mi][ni][rr];
        float v1 = acc1[mi][ni][rr];
        if constexpr (EPI == EPI2_XG) {
          out0[idx] = f2bf(v0);                 // xin raw
          out1[idx] = f2bf(sigm(v1));           // gate
        } else {
          out0[idx] = f2bf(v0 * sigm(v0) * v1); // m = silu(g) * u
        }
      }
    }
  }
}

// ---------------------------------------------------------------------------
// Chunked scan, 2 channels/thread, 64 chunks of 64 steps -> 1024 blocks.
// a_t = sigmoid(z_t); h_t = a_t h_{t-1} + sqrt(1-a_t^2+1e-8) x_t
__global__ void scan_phase1(const f16* __restrict__ z, const u16* __restrict__ xin,
                            float2* __restrict__ ch_h, float2* __restrict__ ch_p) {
  int gtid = blockIdx.x * 256 + threadIdx.x;   // 64 chunks x 4096 pairs
  int c = gtid >> 12;
  int pair = gtid & (NPAIR - 1);
  int b = pair >> 10;                          // DREC/2 = 1024 pairs per batch
  int d = (pair & 1023) * 2;
  size_t base = ((size_t)b * TLEN + (size_t)c * CHUNK) * DREC + d;
  float2 h = {0.f, 0.f}, P = {1.f, 1.f};
#pragma unroll 8
  for (int t = 0; t < CHUNK; ++t) {
    size_t i = base + (size_t)t * DREC;
    f16 z2[2]; *(uint32_t*)z2 = *(const uint32_t*)(z + i);
    u16 x2[2]; *(uint32_t*)x2 = *(const uint32_t*)(xin + i);
    float a0 = sigm((float)z2[0]), a1 = sigm((float)z2[1]);
    h.x = a0 * h.x + sqrtf(1.f - a0 * a0 + 1e-8f) * b2f(x2[0]);
    h.y = a1 * h.y + sqrtf(1.f - a1 * a1 + 1e-8f) * b2f(x2[1]);
    P.x *= a0; P.y *= a1;
  }
  ch_h[gtid] = h;
  ch_p[gtid] = P;
}

__global__ void scan_phase2(float2* __restrict__ ch_h, const float2* __restrict__ ch_p) {
  int pair = blockIdx.x * 256 + threadIdx.x;   // 4096 pairs
  float2 H = {0.f, 0.f};
#pragma unroll
  for (int c = 0; c < NCH; ++c) {
    int i = c * NPAIR + pair;
    float2 he = ch_h[i];
    float2 P  = ch_p[i];
    ch_h[i] = H;          // carry-in for this chunk
    H.x = he.x + P.x * H.x;
    H.y = he.y + P.y * H.y;
  }
}

// Phase 3: rescan with carry-in; y = gate*h written IN PLACE over gate.
__global__ void scan_phase3(const f16* __restrict__ z, const u16* __restrict__ xin,
                            u16* gate_y, const float2* __restrict__ ch_h) {
  int gtid = blockIdx.x * 256 + threadIdx.x;
  int c = gtid >> 12;
  int pair = gtid & (NPAIR - 1);
  int b = pair >> 10;
  int d = (pair & 1023) * 2;
  size_t base = ((size_t)b * TLEN + (size_t)c * CHUNK) * DREC + d;
  float2 h = ch_h[gtid];
#pragma unroll 8
  for (int t = 0; t < CHUNK; ++t) {
    size_t i = base + (size_t)t * DREC;
    f16 z2[2]; *(uint32_t*)z2 = *(const uint32_t*)(z + i);
    u16 x2[2]; *(uint32_t*)x2 = *(const uint32_t*)(xin + i);
    u16 g2[2]; *(uint32_t*)g2 = *(const uint32_t*)(gate_y + i);
    float a0 = sigm((float)z2[0]), a1 = sigm((float)z2[1]);
    h.x = a0 * h.x + sqrtf(1.f - a0 * a0 + 1e-8f) * b2f(x2[0]);
    h.y = a1 * h.y + sqrtf(1.f - a1 * a1 + 1e-8f) * b2f(x2[1]);
    u16 o2[2];
    o2[0] = f2bf(b2f(g2[0]) * h.x);
    o2[1] = f2bf(b2f(g2[1]) * h.y);
    *(uint32_t*)(gate_y + i) = *(uint32_t*)o2;
  }
}

// ---------------------------------------------------------------------------
extern "C" void kernel_launch(void* const* d_in, const int* in_sizes, int n_in,
                              void* d_out, int out_size, void* d_ws, size_t ws_size,
                              hipStream_t stream) {
  const float* x      = (const float*)d_in[0];
  const float* ln1    = (const float*)d_in[1];
  const float* ln2    = (const float*)d_in[2];
  const float* w_in   = (const float*)d_in[3];
  const float* w_gate = (const float*)d_in[4];
  const float* a_par  = (const float*)d_in[5];
  const float* w_a    = (const float*)d_in[6];
  const float* w_out  = (const float*)d_in[7];
  const float* w_mg   = (const float*)d_in[8];
  const float* w_mu   = (const float*)d_in[9];
  const float* w_md   = (const float*)d_in[10];
  float* out = (float*)d_out;
  char* ws = (char*)d_ws;

  const size_t MB = 1024ull * 1024ull;
  // bf16 weights: 0..44 MB
  u16* wb_in  = (u16*)(ws + 0 * MB);    // 4 MB  (dead after step 3)
  u16* wb_gt  = (u16*)(ws + 4 * MB);    // 4 MB  (dead after step 3)
  u16* wb_a   = (u16*)(ws + 8 * MB);    // 8 MB
  u16* wb_out = (u16*)(ws + 16 * MB);   // 4 MB
  u16* wb_mg  = (u16*)(ws + 20 * MB);   // 8 MB
  u16* wb_mu  = (u16*)(ws + 28 * MB);   // 8 MB
  u16* wb_md  = (u16*)(ws + 36 * MB);   // 8 MB
  // activations (time-multiplexed)
  u16* hbuf  = (u16*)(ws + 44 * MB);    // 32 MB: h, later h2
  f16* zbuf  = (f16*)(ws + 44 * MB);    // 64 MB: a-logits (over dead h)
  u16* gateb = (u16*)(ws + 108 * MB);   // 64 MB: gate -> y -> dead
  u16* mbuf  = (u16*)(ws + 108 * MB);   // 64 MB: mlp half (after y dead)
  // chunk summaries (2 MB each) overlay wb_in/wb_gt (dead once scan starts)
  float2* chh = (float2*)(ws + 0 * MB);
  float2* chp = (float2*)(ws + 2 * MB);
  u16* xinb = (u16*)d_out;              // d_out as scratch: xin, then xr
  // high-water: 173 MB of ws

  // 1) all weights -> bf16 in one launch
  f2b_all<<<22528, 256, 0, stream>>>(w_in, w_gate, w_a, w_out, w_mg, w_mu, w_md,
                                     wb_in, wb_gt, wb_a, wb_out, wb_mg, wb_mu, wb_md);

  // 2) h = rmsnorm(x, ln1)
  rmsnorm_kernel<<<BT, 256, 0, stream>>>(x, ln1, hbuf);

  // 3) fused: xin = h@w_in^T (raw, -> d_out), gate = sigmoid(h@w_gate^T)
  gemm2<EPI2_XG><<<dim3(BT / BM, DREC / 64), 256, 0, stream>>>(
      hbuf, wb_in, wb_gt, HID, DREC, HID, HID, xinb, gateb);

  // 4) z = a_param + xin@w_a^T  (fp16 logits)
  gemm1<EPI_LOGIT><<<dim3(BT / BM, DREC / BN), 256, 0, stream>>>(
      xinb, wb_a, DREC, DREC, DREC, DREC, nullptr, zbuf, a_par);

  // 5) chunked scan; y = gate*h in place over gate
  scan_phase1<<<NCH * NPAIR / 256, 256, 0, stream>>>(zbuf, xinb, chh, chp);
  scan_phase2<<<NPAIR / 256, 256, 0, stream>>>(chh, chp);
  scan_phase3<<<NCH * NPAIR / 256, 256, 0, stream>>>(zbuf, xinb, gateb, chh);

  // 6) xr = x + y@w_out^T  -> d_out (xin dead)
  gemm1<EPI_ADDF><<<dim3(BT / BM, HID / BN), 256, 0, stream>>>(
      gateb, wb_out, DREC, HID, DREC, DREC, out, nullptr, x);

  // 7) h2 = rmsnorm(xr, ln2)
  rmsnorm_kernel<<<BT, 256, 0, stream>>>(out, ln2, hbuf);

  // 8) MLP in two INTER halves; down-GEMM accumulates into d_out in place
  for (int half = 0; half < 2; ++half) {
    const u16* wmg_h = wb_mg + (size_t)half * 2048 * HID;
    const u16* wmu_h = wb_mu + (size_t)half * 2048 * HID;
    const u16* wmd_h = wb_md + (size_t)half * 2048;      // column slice, ldW=INTER
    gemm2<EPI2_SM><<<dim3(BT / BM, 2048 / 64), 256, 0, stream>>>(
        hbuf, wmg_h, wmu_h, HID, 2048, HID, HID, mbuf, nullptr);
    gemm1<EPI_ADDF><<<dim3(BT / BM, HID / BN), 256, 0, stream>>>(
        mbuf, wmd_h, 2048, HID, 2048, INTER, out, nullptr, out);
  }
}